// Round 7
// baseline (378.118 us; speedup 1.0000x reference)
//
#include <hip/hip_runtime.h>
#include <hip/hip_bf16.h>
#include <math.h>

#define B_TOT 512
#define SEQ   200
#define D     128
#define DH    256
#define DFF   512
#define LPAD  256
#define PADL  56
#define NLAY  2
#define SSTRIP 140  // scan LDS strip stride (floats): strip = 8 pos x 16 ch + pad

typedef __attribute__((ext_vector_type(8))) short bf16x8;
typedef __attribute__((ext_vector_type(4))) float floatx4;
typedef __attribute__((ext_vector_type(2))) float floatx2;

static __device__ inline float bf2f(ushort u) {
    union { unsigned int i; float f; } v; v.i = ((unsigned int)u) << 16; return v.f;
}
static __device__ inline ushort f2bf(float x) {
    union { float f; unsigned int i; } v; v.f = x;
    unsigned int r = (v.i + 0x7FFFu + ((v.i >> 16) & 1u)) >> 16;   // RNE
    return (ushort)r;
}
// HW packed f32x2 -> bf16x2 (v_cvt_pk_bf16_f32 on gfx950), RNE
static __device__ inline unsigned int pkbf(float a, float b) {
    union { __hip_bfloat162 h; unsigned int u; } v;
    v.h = __float22bfloat162_rn(make_float2(a, b));
    return v.u;
}
// async global->LDS, 16B per lane; LDS dest = wave-uniform base + lane*16
static __device__ inline void gld_lds16(const void* g, void* l) {
    __builtin_amdgcn_global_load_lds(
        (const __attribute__((address_space(1))) unsigned int*)g,
        (__attribute__((address_space(3))) unsigned int*)l, 16, 0, 0);
}

// H layout: [b][g(8)][p(re/im)][s(200)][32 ch] bf16. k in 0..511: k<256 re, else im.
static __device__ inline size_t haddr(int b, int s, int k) {
    int p  = k >> 8;
    int ch = k & 255;
    int g  = ch >> 5;
    int cl = ch & 31;
    return (((((size_t)b * 8 + g) * 2 + p) * SEQ + s) * 32 + cl);
}

// ---------------------------------------------------------------------------
// Unified setup: pre-swizzled weight images + lambda powers/scales.
// ---------------------------------------------------------------------------
__global__ void setup_all_kernel(const float* __restrict__ params_log,
                                 const float* __restrict__ in_br,
                                 const float* __restrict__ in_bi,
                                 const float* __restrict__ in_wr,
                                 const float* __restrict__ in_wi,
                                 const float* __restrict__ out_wr,
                                 const float* __restrict__ out_wi,
                                 const float* __restrict__ w1,
                                 const float* __restrict__ w2,
                                 ushort* __restrict__ Winb,
                                 ushort* __restrict__ W2effb,
                                 ushort* __restrict__ w1b,
                                 ushort* __restrict__ w2b,
                                 float* __restrict__ lam_pow,
                                 float* __restrict__ scale_in,
                                 float* __restrict__ bias_in)
{
    int idx = blockIdx.x * blockDim.x + threadIdx.x;   // NLAY*65536
    int li = idx >> 16;
    int e  = idx & 65535;

    {   // inproj Ws image
        int gp = e >> 12, rem = e & 4095;
        int q = rem >> 3, e8 = rem & 7;
        int r = q >> 4, cs = q & 15;
        int c16 = cs ^ (r & 7);
        int n = (r < 16) ? (gp * 16 + r) : (256 + gp * 16 + (r - 16));
        int d = c16 * 8 + e8;
        float wv = (n < DH) ? in_wr[((size_t)li * DH + n) * D + d]
                            : in_wi[((size_t)li * DH + (n - DH)) * D + d];
        Winb[idx] = f2bf(wv);
    }
    {   // out-proj W2eff image
        int k0c = e >> 13, rem = e & 8191;
        int q = rem >> 3, e8 = rem & 7;
        int r = q >> 3, cs = q & 7;
        int c16 = cs ^ (r & 7);
        int k = k0c * 64 + c16 * 8 + e8;
        float w2v = (k < DH) ? out_wr[((size_t)li * D + r) * DH + k]
                             : -out_wi[((size_t)li * D + r) * DH + (k - DH)];
        W2effb[idx] = f2bf(w2v);
    }
    {   // ffn W1 image: logical [512][128]
        int row = e >> 7, col = e & 127;
        int ffc = row >> 7, rl = row & 127;
        int c16 = col >> 3, e8 = col & 7;
        int cs = c16 ^ (rl & 7);
        w1b[li * 65536 + ffc * 16384 + rl * 128 + cs * 8 + e8] = f2bf(w1[idx]);
    }
    {   // ffn W2 image: logical [128][512]
        int dd2 = e >> 9, kk = e & 511;
        int ffc = kk >> 7, klc = kk & 127;
        int c16 = klc >> 3, e8 = klc & 7;
        int cs = c16 ^ (dd2 & 7);
        w2b[li * 65536 + ffc * 16384 + dd2 * 128 + cs * 8 + e8] = f2bf(w2[idx]);
    }

    if (blockIdx.x < NLAY) {
        int pli = blockIdx.x;
        int c = threadIdx.x;
        const float* pl = params_log + (size_t)pli * 3 * DH;
        float nu = expf(pl[c]);
        float th = expf(pl[DH + c]);
        float ga = expf(pl[2 * DH + c]);
        float mag = expf(-nu);
        float lr = mag * cosf(th);
        float lim = mag * sinf(th);
        float2* lp = (float2*)(lam_pow + (size_t)pli * 65536) + (size_t)c * 128;
        float pr = lr, pi = lim;
        lp[0] = make_float2(pr, pi);
        for (int k = 1; k < 128; ++k) {
            float nr = pr * lr - pi * lim;
            float ni = pr * lim + pi * lr;
            pr = nr; pi = ni;
            lp[k] = make_float2(pr, pi);
        }
        scale_in[pli * 2 * DH + c]      = ga;
        scale_in[pli * 2 * DH + DH + c] = ga;
        bias_in[pli * 2 * DH + c]       = in_br[pli * DH + c] * ga;
        bias_in[pli * 2 * DH + DH + c]  = in_bi[pli * DH + c] * ga;
    }
}

// ---------------------------------------------------------------------------
// Embedding gather + LayerNorm -> bf16 x (R20: skip causally dead rows).
// R24: the LAST block instead builds the compacted rowmap (fused, -1 kernel).
// ---------------------------------------------------------------------------
__global__ __launch_bounds__(256) void embed_ln_kernel(
    const float* __restrict__ emb, const int* __restrict__ seq,
    const int* __restrict__ lenp,
    const float* __restrict__ g, const float* __restrict__ bt,
    ushort* __restrict__ x,
    int Bc, int* __restrict__ total, int* __restrict__ rowmap)
{
    if (blockIdx.x == gridDim.x - 1) {
        // rowmap build: prefix scan of lengths (pair-per-thread, Bc <= 512)
        __shared__ int ps[257];
        int t = threadIdx.x;
        int b0_ = 2 * t, b1_ = 2 * t + 1;
        int lv0 = (b0_ < Bc) ? lenp[b0_] : 0;
        int lv1 = (b1_ < Bc) ? lenp[b1_] : 0;
        ps[t + 1] = lv0 + lv1;
        if (t == 0) ps[0] = 0;
        __syncthreads();
        for (int ofs = 1; ofs < 256; ofs <<= 1) {
            int v = ps[t + 1];
            int vv = (t + 1 > ofs) ? ps[t + 1 - ofs] : 0;
            __syncthreads();
            ps[t + 1] = v + vv;
            __syncthreads();
        }
        if (t == 255) total[0] = ps[256];
        int base = ps[t];
        int rb0 = b0_ * SEQ, rb1 = b1_ * SEQ;
        for (int s = 0; s < lv0; ++s) rowmap[base + s] = rb0 + s;
        base += lv0;
        for (int s = 0; s < lv1; ++s) rowmap[base + s] = rb1 + s;
        return;
    }
    int row  = blockIdx.x * 4 + (threadIdx.x >> 6);
    int lane = threadIdx.x & 63;
    int b = row / SEQ, s = row - b * SEQ;
    if (s >= lenp[b]) return;
    int item = seq[row];
    float2 v = *(const float2*)(emb + (size_t)item * D + lane * 2);
    float ssum = v.x + v.y;
#pragma unroll
    for (int o = 32; o > 0; o >>= 1) ssum += __shfl_xor(ssum, o);
    float mu = ssum * (1.0f / D);
    float d0 = v.x - mu, d1 = v.y - mu;
    float vs = d0 * d0 + d1 * d1;
#pragma unroll
    for (int o = 32; o > 0; o >>= 1) vs += __shfl_xor(vs, o);
    float rstd = rsqrtf(vs * (1.0f / D) + 1e-5f);
    float2 gg = *(const float2*)(g + lane * 2);
    float2 bb = *(const float2*)(bt + lane * 2);
    unsigned int o2 = pkbf(d0 * rstd * gg.x + bb.x, d1 * rstd * gg.y + bb.y);
    *(unsigned int*)(x + (size_t)row * D + lane * 2) = o2;
}

// ---------------------------------------------------------------------------
// FUSED in-proj + exact tree scan (R24 strip layout + shuffle tree).
// R27: XCD-aware bijective block swizzle.
// R28: (a) lambda-power prefetch hoisted BEFORE the first barrier — the
//      staging barrier's vmcnt(0) drain completes them for free (was a
//      serial L2-latency stall at the head of the scan phase);
//      (b) single-phase MFMA when tile_max <= 6 (~56% of blocks): stage B
//      is empty and rq>=2 waves have no tiles, so the 4-barrier A/B
//      structure collapses to ONE barrier (block-uniform branch).
// ---------------------------------------------------------------------------
template <bool LAST>
__global__ __launch_bounds__(512) void inproj_scan_kernel(
    const ushort* __restrict__ X, const ushort* __restrict__ Win,
    ushort* __restrict__ H, const float2* __restrict__ lamT,
    const int* __restrict__ seq, const int* __restrict__ lenp,
    const float* __restrict__ scale_in, const float* __restrict__ bias_in)
{
    __shared__ __align__(16) char smem[36864];   // Ws 8192 + xs 28672 (phase A)
    __shared__ __align__(16) float mkfS[32 * 12];
    char*  Wsm = smem;                           // [32][128] bf16, swizzled
    char*  xs  = smem + 8192;                    // [112][128] bf16, swizzled
    float* stR2 = (float*)smem;                  // strip layout, 4480 floats
    float* stI2 = stR2 + 32 * SSTRIP;            // ends at 35840 B

    // XCD swizzle (bijective: nwg = 16*Bc is divisible by 8)
    int flat = blockIdx.y * 16 + blockIdx.x;
    int cpx  = (gridDim.y * 16) >> 3;
    int swz  = (flat & 7) * cpx + (flat >> 3);
    int gp = swz & 15, b = swz >> 4;

    int tid = threadIdx.x;
    int l = tid & 63, w = tid >> 6;              // 8 waves
    int ct = w & 1;                              // 0=re tile, 1=im tile
    int rq = w >> 1;                             // row quarter 0..3
    int lr = l & 15, lq = l >> 4;
    int wbase = tid & ~63;

    int c  = tid >> 5;                           // scan channel 0..15
    int tl = tid & 31;                           // chunk 0..31 (in-wave)
    int t0 = tl * 8;
    int lbase = l & 32;                          // channel-half base lane
    int coff = (c >> 2) * 36 + (c & 3) * 8;      // channel offset within strip

    // R20 causal bounds (block-uniform)
    int s_b = lenp[b] - 1;                       // 0..199
    int tile_max = s_b >> 4;                     // needed MFMA tiles 0..tile_max
    int nrows = (tile_max + 1) * 16;             // staged rows (tile-rounded)
    int tb = s_b + PADL;                         // last needed padded position
    bool activeT = (t0 <= tb);

    // ---- Phase A: async Ws stage + x stage A (rows 0..min(112,nrows))
    const ushort* xrow = X + (size_t)b * SEQ * 128;
    gld_lds16(Win + (size_t)gp * 4096 + (size_t)tid * 8,
              Wsm + (size_t)wbase * 16);
    int nrA = nrows < 112 ? nrows : 112;
#pragma unroll
    for (int it = 0; it < 4; ++it) {
        int rbase = it * 32 + w * 4;             // wave-uniform base row
        int r = rbase + lq;
        int cs = lr ^ (r & 7);
        if (r < nrA)
            gld_lds16(xrow + (size_t)r * 128 + cs * 8, xs + rbase * 256);
    }

    // R28a: lambda-power prefetch issued HERE — completed for free by the
    // staging barrier's vmcnt(0) drain (loads are independent of LDS).
    const float2* myl = lamT + (size_t)(gp * 16 + c) * 128;
    float2 l14[4];
#pragma unroll
    for (int k = 0; k < 4; ++k) l14[k] = myl[k];
    float2 myl9 = myl[8];
    float2 lam_e[3];                             // levels half=32/64/128
#pragma unroll
    for (int i = 0; i < 3; ++i) {
        int half = 32 << i;
        int off = t0 & ((half << 1) - 1);
        int e = off - half;
        lam_e[i] = myl[e < 0 ? 0 : e];
    }
    float2 l7;                                   // lambda^7 = l^4 * l^3
    l7.x = l14[3].x * l14[2].x - l14[3].y * l14[2].y;
    l7.y = l14[3].x * l14[2].y + l14[3].y * l14[2].x;

    if (tid < LPAD) {
        int t = tid;
        float m = 0.f;
        if (t >= PADL) m = (seq[(size_t)b * SEQ + (t - PADL)] > 0) ? 1.f : 0.f;
        mkfS[(t >> 3) * 12 + (t & 7)] = m;
    }
    __syncthreads();

    bf16x8 wf[4];
#pragma unroll
    for (int kk = 0; kk < 4; ++kk) {
        int ca = kk * 4 + lq;
        int wr = ct * 16 + lr;
        wf[kk] = *(const bf16x8*)(Wsm + wr * 256 + ((ca ^ (wr & 7)) * 16));
    }
    int tstart = rq ? (3 * rq + 1) : 0;          // 0 / 4 / 7 / 10
    int tcnt   = rq ? 3 : 4;
    floatx4 acc[4];
#pragma unroll
    for (int tt = 0; tt < 4; ++tt) acc[tt] = (floatx4)0.f;

    if (nrows <= 112) {
        // R28b single-phase: all needed tiles (<=6) live in stage A; rq>=2
        // waves have tstart >= 7 > tile_max so they contribute nothing.
        if (rq < 2) {
#pragma unroll
            for (int tt = 0; tt < 4; ++tt) {
                if (tt < tcnt && (tstart + tt) <= tile_max) {
                    int t  = tstart + tt;
                    int ar = t * 16 + lr;
#pragma unroll
                    for (int kk = 0; kk < 4; ++kk) {
                        int ca = kk * 4 + lq;
                        bf16x8 af = *(const bf16x8*)(xs + ar * 256 + ((ca ^ (ar & 7)) * 16));
                        acc[tt] = __builtin_amdgcn_mfma_f32_16x16x32_bf16(wf[kk], af, acc[tt], 0, 0, 0);
                    }
                }
            }
        }
        __syncthreads();
    } else {
        if (rq < 2) {
#pragma unroll
            for (int tt = 0; tt < 4; ++tt) {
                if (tt < tcnt && (tstart + tt) <= tile_max) {
                    int t  = tstart + tt;
                    int ar = t * 16 + lr;
#pragma unroll
                    for (int kk = 0; kk < 4; ++kk) {
                        int ca = kk * 4 + lq;
                        bf16x8 af = *(const bf16x8*)(xs + ar * 256 + ((ca ^ (ar & 7)) * 16));
                        acc[tt] = __builtin_amdgcn_mfma_f32_16x16x32_bf16(wf[kk], af, acc[tt], 0, 0, 0);
                    }
                }
            }
        }
        __syncthreads();

        // stage B: rows 112..nrows-1 -> xs local rows 0..
        {
            int nrB = nrows < 200 ? nrows : 200;
#pragma unroll
            for (int it = 0; it < 3; ++it) {
                int rbase = it * 32 + w * 4;     // local rows 0..95
                int rl_ = rbase + lq;
                int gr = 112 + rl_;
                int cs = lr ^ (rl_ & 7);
                if (gr < nrB)
                    gld_lds16(xrow + (size_t)gr * 128 + cs * 8, xs + rbase * 256);
            }
        }
        __syncthreads();

        if (rq >= 2) {
#pragma unroll
            for (int tt = 0; tt < 4; ++tt) {
                if (tt < tcnt && (tstart + tt) <= tile_max) {
                    int t  = tstart + tt;
                    int ar = (t - 7) * 16 + lr;
#pragma unroll
                    for (int kk = 0; kk < 4; ++kk) {
                        int ca = kk * 4 + lq;
                        bf16x8 af = *(const bf16x8*)(xs + ar * 256 + ((ca ^ (ar & 7)) * 16));
                        acc[tt] = __builtin_amdgcn_mfma_f32_16x16x32_bf16(wf[kk], af, acc[tt], 0, 0, 0);
                    }
                }
            }
        }
        __syncthreads();
    }

    // ---- Phase B: zero pad strips (pos 0..55 = strips 0..6) + epilogue
    for (int idx = tid; idx < 7 * SSTRIP; idx += 512) { stR2[idx] = 0.f; stI2[idx] = 0.f; }
    {
        float4 g4 = *(const float4*)(scale_in + ct * 256 + gp * 16 + lq * 4);
        float4 b4 = *(const float4*)(bias_in  + ct * 256 + gp * 16 + lq * 4);
        float* base = ct ? stI2 : stR2;
#pragma unroll
        for (int tt = 0; tt < 4; ++tt) {
            if (tt < tcnt && (tstart + tt) <= tile_max) {
                int t = tstart + tt;
                int s = t * 16 + lr;
                if (s <= s_b) {
                    // pos = s + 56; strip = 2t+7+(lr>>3); off = lr&7
                    float* dst = base + (2 * t + 7 + (lr >> 3)) * SSTRIP
                               + lq * 36 + (lr & 7);
                    dst[0]  = acc[tt][0] * g4.x + b4.x;
                    dst[8]  = acc[tt][1] * g4.y + b4.y;
                    dst[16] = acc[tt][2] * g4.z + b4.z;
                    dst[24] = acc[tt][3] * g4.w + b4.w;
                }
            }
        }
    }
    __syncthreads();

    // ---- Scan: conflict-free b128 loads, pair-packed levels, shuffle tree
    floatx2 Xr[4], Xi[4], Mf[4];
    {
        const float* pr = stR2 + tl * SSTRIP + coff;
        const float* pi = stI2 + tl * SSTRIP + coff;
        floatx4 r0 = *(const floatx4*)pr;
        floatx4 r1 = *(const floatx4*)(pr + 4);
        floatx4 i0 = *(const floatx4*)pi;
        floatx4 i1 = *(const floatx4*)(pi + 4);
        floatx4 m0 = *(const floatx4*)(mkfS + tl * 12);
        floatx4 m1 = *(const floatx4*)(mkfS + tl * 12 + 4);
        Xr[0] = floatx2{r0[0], r0[1]}; Xr[1] = floatx2{r0[2], r0[3]};
        Xr[2] = floatx2{r1[0], r1[1]}; Xr[3] = floatx2{r1[2], r1[3]};
        Xi[0] = floatx2{i0[0], i0[1]}; Xi[1] = floatx2{i0[2], i0[3]};
        Xi[2] = floatx2{i1[0], i1[1]}; Xi[3] = floatx2{i1[2], i1[3]};
        Mf[0] = floatx2{m0[0], m0[1]}; Mf[1] = floatx2{m0[2], m0[3]};
        Mf[2] = floatx2{m1[0], m1[1]}; Mf[3] = floatx2{m1[2], m1[3]};
    }

    float l0x = l14[0].x, l0y = l14[0].y;
    floatx2 L01R = floatx2{l14[0].x, l14[1].x};
    floatx2 L01I = floatx2{l14[0].y, l14[1].y};
    floatx2 L23R = floatx2{l14[2].x, l14[3].x};
    floatx2 L23I = floatx2{l14[2].y, l14[3].y};

    if (activeT) {
        // level 1: even -> odd within pairs (scalar)
#pragma unroll
        for (int p = 0; p < 4; ++p) {
            float sr = Xr[p].x * Mf[p].x, si = Xi[p].x * Mf[p].x;
            Xr[p].y += l0x * sr; Xr[p].y -= l0y * si;
            Xi[p].y += l0x * si; Xi[p].y += l0y * sr;
        }
        // level 2: src x1 -> pair1, src x5 -> pair3 (packed)
#pragma unroll
        for (int p = 0; p < 2; ++p) {
            int sp_ = p * 2;                     // source pair 0 / 2
            float sr = Xr[sp_].y * Mf[sp_].y, si = Xi[sp_].y * Mf[sp_].y;
            Xr[sp_ + 1] += sr * L01R; Xr[sp_ + 1] -= si * L01I;
            Xi[sp_ + 1] += si * L01R; Xi[sp_ + 1] += sr * L01I;
        }
        // level 3: src x3 -> pairs 2,3 (packed)
        {
            float sr = Xr[1].y * Mf[1].y, si = Xi[1].y * Mf[1].y;
            Xr[2] += sr * L01R; Xr[2] -= si * L01I;
            Xi[2] += si * L01R; Xi[2] += sr * L01I;
            Xr[3] += sr * L23R; Xr[3] -= si * L23I;
            Xi[3] += si * L23R; Xi[3] += sr * L23I;
        }
    }

    // levels 4-8 via intra-wave shuffles on x7 (scalar, lazy carry)
    float x7r, x7i;
    if (activeT) { x7r = Xr[3].y; x7i = Xi[3].y; }
    else         { x7r = 0.f;     x7i = 0.f; }
    float Ctr = 0.f, Cti = 0.f;
    float m7 = Mf[3].y;
    float pxr = x7r * m7, pxi = x7i * m7;

#define TREE_LEVEL(SRC_TL, TGT, LE)                                          \
    {                                                                        \
        int srcl = lbase | (SRC_TL);                                         \
        float svx = __shfl(pxr, srcl);                                       \
        float svy = __shfl(pxi, srcl);                                       \
        if (activeT && (TGT)) {                                              \
            float2 le = (LE);                                                \
            float cr = le.x * svx - le.y * svy;                              \
            float ci = le.x * svy + le.y * svx;                              \
            Ctr += cr; Cti += ci;                                            \
            x7r += l7.x * cr - l7.y * ci;                                    \
            x7i += l7.x * ci + l7.y * cr;                                    \
            pxr = x7r * m7; pxi = x7i * m7;                                  \
        }                                                                    \
    }

    TREE_LEVEL(tl & ~1,          tl & 1,  l14[0]);                   // half=8
    TREE_LEVEL((tl & ~3)  | 1,   tl & 2,  (tl & 1) ? myl9 : l14[0]); // half=16
    TREE_LEVEL((tl & ~7)  | 3,   tl & 4,  lam_e[0]);                 // half=32
    if (tb >= 64)  TREE_LEVEL((tl & ~15) | 7,  tl & 8,  lam_e[1]);   // half=64
    if (tb >= 128) TREE_LEVEL((tl & ~31) | 15, tl & 16, lam_e[2]);   // half=128
#undef TREE_LEVEL

    // apply accumulated carry to positions 0..6 (x7 already exact)
    if (activeT && (!LAST || (unsigned)(tb - t0) < 7u)) {
        float2 l5, l6;
        l5.x = l14[3].x * l14[0].x - l14[3].y * l14[0].y;
        l5.y = l14[3].x * l14[0].y + l14[3].y * l14[0].x;
        l6.x = l14[3].x * l14[1].x - l14[3].y * l14[1].y;
        l6.y = l14[3].x * l14[1].y + l14[3].y * l14[1].x;
        Xr[0].x += Ctr;                                 Xi[0].x += Cti;
        Xr[0].y += l14[0].x * Ctr; Xr[0].y -= l14[0].y * Cti;
        Xi[0].y += l14[0].x * Cti; Xi[0].y += l14[0].y * Ctr;
        Xr[1].x += l14[1].x * Ctr; Xr[1].x -= l14[1].y * Cti;
        Xi[1].x += l14[1].x * Cti; Xi[1].x += l14[1].y * Ctr;
        Xr[1].y += l14[2].x * Ctr; Xr[1].y -= l14[2].y * Cti;
        Xi[1].y += l14[2].x * Cti; Xi[1].y += l14[2].y * Ctr;
        Xr[2].x += l14[3].x * Ctr; Xr[2].x -= l14[3].y * Cti;
        Xi[2].x += l14[3].x * Cti; Xi[2].x += l14[3].y * Ctr;
        Xr[2].y += l5.x * Ctr;     Xr[2].y -= l5.y * Cti;
        Xi[2].y += l5.x * Cti;     Xi[2].y += l5.y * Ctr;
        Xr[3].x += l6.x * Ctr;     Xr[3].x -= l6.y * Cti;
        Xi[3].x += l6.x * Cti;     Xi[3].x += l6.y * Ctr;
    }
    Xr[3].y = x7r; Xi[3].y = x7i;

    if (LAST) {
        // only position tb is consumed downstream
        if (activeT && (unsigned)(tb - t0) < 8u) {
#pragma unroll
            for (int k = 0; k < 8; ++k)
                if (t0 + k == tb) {
                    float vr = (k & 1) ? Xr[k >> 1].y : Xr[k >> 1].x;
                    float vi = (k & 1) ? Xi[k >> 1].y : Xi[k >> 1].x;
                    stR2[tl * SSTRIP + coff + k] = vr;
                    stI2[tl * SSTRIP + coff + k] = vi;
                }
        }
    } else {
        // pad threads (chunks fully < PADL) write rows never read
        if (activeT && tl >= 7) {
            floatx4 r0 = floatx4{Xr[0].x, Xr[0].y, Xr[1].x, Xr[1].y};
            floatx4 r1 = floatx4{Xr[2].x, Xr[2].y, Xr[3].x, Xr[3].y};
            floatx4 i0 = floatx4{Xi[0].x, Xi[0].y, Xi[1].x, Xi[1].y};
            floatx4 i1 = floatx4{Xi[2].x, Xi[2].y, Xi[3].x, Xi[3].y};
            *(floatx4*)(stR2 + tl * SSTRIP + coff)     = r0;
            *(floatx4*)(stR2 + tl * SSTRIP + coff + 4) = r1;
            *(floatx4*)(stI2 + tl * SSTRIP + coff)     = i0;
            *(floatx4*)(stI2 + tl * SSTRIP + coff + 4) = i1;
        }
    }
    __syncthreads();

    if (LAST) {
        if (tid < 32) {
            int p = tid >> 4, cc = tid & 15;
            int fi = (tb >> 3) * SSTRIP + (cc >> 2) * 36 + (cc & 3) * 8 + (tb & 7);
            float v = (p ? stI2 : stR2)[fi];
            H[(size_t)b * 512 + p * 256 + gp * 16 + cc] = f2bf(v);
        }
    } else {
        int g  = gp >> 1;
        int hc = (gp & 1) * 16;
        ushort* baseg = H + (size_t)(b * 8 + g) * 2 * SEQ * 32 + hc;
#pragma unroll
        for (int it = 0; it < 4; ++it) {
            int idx4 = it * 512 + tid;
            if (idx4 < 2 * SEQ * 4) {
                int q  = idx4 & 3;
                int ps = idx4 >> 2;
                int p  = ps >= SEQ;
                int s  = ps - p * SEQ;
                if (s > s_b) continue;           // causally dead, never read
                // pos = s + 56: strip = (s+56)>>3, off = s&7 (56 % 8 == 0)
                const float* sp = (p ? stI2 : stR2)
                                + ((s + PADL) >> 3) * SSTRIP + q * 36 + (s & 7);
                float a0 = sp[0], a1 = sp[8], a2 = sp[16], a3 = sp[24];
                uint2 raw;
                raw.x = pkbf(a0, a1);
                raw.y = pkbf(a2, a3);
                *(uint2*)(baseg + (size_t)ps * 32 + q * 4) = raw;
            }
        }
    }
}

// ---------------------------------------------------------------------------
// Out-proj GEMM (full path). R27: double-buffered As/Bs, prefetch distance 1.
// ---------------------------------------------------------------------------
__global__ __launch_bounds__(256) void outproj_kernel(
    const ushort* __restrict__ A, const ushort* __restrict__ Wimg,
    ushort* __restrict__ Cout,
    const int* __restrict__ rowmap, const int* __restrict__ totalp,
    const float* __restrict__ e0,
    const ushort* __restrict__ res,
    const float* __restrict__ lng, const float* __restrict__ lnb)
{
    int m0 = blockIdx.x * 64;
    int total = totalp[0];
    if (m0 >= total) return;
    __shared__ __align__(16) char As[2][8192];
    __shared__ __align__(16) char Bs[2][16384];
    __shared__ float2 lnS[2][64];
    int tid = threadIdx.x;
    int l = tid & 63, w = tid >> 6;              // 4 waves
    int chh = w >> 1;                            // ch half 0..1 (64 ch)
    int rh  = w & 1;                             // row half 0..1 (32 rows)
    int lr = l & 15, lq = l >> 4;
    int wbase = tid & ~63;

    int cst = tid & 7;
    int rr  = tid >> 3;                          // 0..31
    int sb[2], ss[2];
#pragma unroll
    for (int it = 0; it < 2; ++it) {
        int gr = m0 + it * 32 + rr;
        if (gr >= total) gr = total - 1;
        int rm = rowmap[gr];
        sb[it] = rm / SEQ; ss[it] = rm - sb[it] * SEQ;
    }

    // prologue: stage chunk 0 (W via gld_lds, A via reg+ds_write)
    {
#pragma unroll
        for (int it = 0; it < 4; ++it)
            gld_lds16(Wimg + (size_t)(it * 256 + tid) * 8,
                      Bs[0] + (size_t)(it * 256 + wbase) * 16);
#pragma unroll
        for (int it = 0; it < 2; ++it) {
            int r = it * 32 + rr;
            uint4 va = *(const uint4*)(A + haddr(sb[it], ss[it], cst * 8));
            *(uint4*)(As[0] + r * 128 + ((cst ^ (r & 7)) * 16)) = va;
        }
    }
    __syncthreads();

    floatx4 acc[4][2];
#pragma unroll
    for (int i = 0; i < 4; ++i)
#pragma unroll
        for (int j = 0; j < 2; ++j) acc[i][j] = (floatx4)0.f;

    for (int k0c = 0; k0c < 8; ++k0c) {
        int cur = k0c & 1, nb = cur ^ 1;
        uint4 van[2];
        if (k0c < 7) {
            const ushort* img = Wimg + (size_t)(k0c + 1) * 8192;
#pragma unroll
            for (int it = 0; it < 4; ++it)
                gld_lds16(img + (size_t)(it * 256 + tid) * 8,
                          Bs[nb] + (size_t)(it * 256 + wbase) * 16);
#pragma unroll
            for (int it = 0; it < 2; ++it)
                van[it] = *(const uint4*)(A + haddr(sb[it], ss[it],
                                                   (k0c + 1) * 64 + cst * 8));
        }
        const char* Asb = As[cur];
        const char* Bsb = Bs[cur];
#pragma unroll
        for (int kk = 0; kk < 2; ++kk) {
            bf16x8 wf[4], af[2];
            int ca = kk * 4 + lq;
#pragma unroll
            for (int i = 0; i < 4; ++i) {
                int rb = chh * 64 + i * 16 + lr;
                wf[i] = *(const bf16x8*)(Bsb + rb * 128 + ((ca ^ (rb & 7)) * 16));
            }
#pragma unroll
            for (int j = 0; j < 2; ++j) {
                int ra = rh * 32 + j * 16 + lr;
                af[j] = *(const bf16x8*)(Asb + ra * 128 + ((ca ^ (ra & 7)) * 16));
            }
#pragma unroll
            for (int i = 0; i < 4; ++i)
#pragma unroll
                for (int j = 0; j < 2; ++j)
                    acc[i][j] = __builtin_amdgcn_mfma_f32_16x16x32_bf16(
                        wf[i], af[j], acc[i][j], 0, 0, 0);
        }
        if (k0c < 7) {
#pragma unroll
            for (int it = 0; it < 2; ++it) {
                int r = it * 32 + rr;
                *(uint4*)(As[nb] + r * 128 + ((cst ^ (r & 7)) * 16)) = van[it];
            }
        }
        __syncthreads();
    }

    int chb[4], arow[2], rmj[2];
#pragma unroll
    for (int i = 0; i < 4; ++i) chb[i] = chh * 64 + i * 16 + lq * 4;
#pragma unroll
    for (int j = 0; j < 2; ++j) {
        arow[j] = m0 + rh * 32 + j * 16 + lr;
        int rc = arow[j] < total ? arow[j] : total - 1;
        rmj[j] = rowmap[rc];
    }

    {
        float4 bias[4], gv[4], bv[4];
#pragma unroll
        for (int i = 0; i < 4; ++i) {
            bias[i] = *(const float4*)(e0 + chb[i]);
            gv[i]   = *(const float4*)(lng + chb[i]);
            bv[i]   = *(const float4*)(lnb + chb[i]);
        }
#pragma unroll
        for (int j = 0; j < 2; ++j) {
#pragma unroll
            for (int i = 0; i < 4; ++i) {
                ushort4 r4 = *(const ushort4*)(res + (size_t)rmj[j] * 128 + chb[i]);
                acc[i][j][0] += ((const float*)&bias[i])[0] + bf2f(r4.x);
                acc[i][j][1] += ((const float*)&bias[i])[1] + bf2f(r4.y);
                acc[i][j][2] += ((const float*)&bias[i])[2] + bf2f(r4.z);
                acc[i][j][3] += ((const float*)&bias[i])[3] + bf2f(r4.w);
            }
        }
#pragma unroll
        for (int j = 0; j < 2; ++j) {
            float s = 0.f, q = 0.f;
#pragma unroll
            for (int i = 0; i < 4; ++i)
#pragma unroll
                for (int reg = 0; reg < 4; ++reg) {
                    float v = acc[i][j][reg];
                    s += v; q += v * v;
                }
            s += __shfl_xor(s, 16); q += __shfl_xor(q, 16);
            s += __shfl_xor(s, 32); q += __shfl_xor(q, 32);
            if (lq == 0) lnS[chh][rh * 32 + j * 16 + lr] = make_float2(s, q);
        }
        __syncthreads();
#pragma unroll
        for (int j = 0; j < 2; ++j) {
            int rl = rh * 32 + j * 16 + lr;
            float2 s0 = lnS[0][rl], s1 = lnS[1][rl];
            float mu  = (s0.x + s1.x) * (1.0f / 128.0f);
            float var = (s0.y + s1.y) * (1.0f / 128.0f) - mu * mu;
            float rstd = rsqrtf(var + 1e-5f);
            if (arow[j] < total) {
#pragma unroll
                for (int i = 0; i < 4; ++i) {
                    uint2 u;
                    u.x = pkbf((acc[i][j][0] - mu) * rstd * ((const float*)&gv[i])[0] + ((const float*)&bv[i])[0],
                               (acc[i][j][1] - mu) * rstd * ((const float*)&gv[i])[1] + ((const float*)&bv[i])[1]);
                    u.y = pkbf((acc[i][j][2] - mu) * rstd * ((const float*)&gv[i])[2] + ((const float*)&bv[i])[2],
                               (acc[i][j][3] - mu) * rstd * ((const float*)&gv[i])[3] + ((const float*)&bv[i])[3]);
                    *(uint2*)(Cout + (size_t)rmj[j] * 128 + chb[i]) = u;
                }
            }
        }
    }
}

// ---------------------------------------------------------------------------
// Out-proj LAST (R19): compact M=Bc rows from Hc[b][512]. R27: same
// double-buffered prefetch-1 pipeline as outproj_kernel.
// ---------------------------------------------------------------------------
__global__ __launch_bounds__(256) void outproj_last_kernel(
    const ushort* __restrict__ Hc, const ushort* __restrict__ Wimg,
    ushort* __restrict__ xc, int Bc,
    const float* __restrict__ e0,
    const ushort* __restrict__ Xres, const int* __restrict__ lenp,
    const float* __restrict__ lng, const float* __restrict__ lnb)
{
    __shared__ __align__(16) char As[2][8192];
    __shared__ __align__(16) char Bs[2][16384];
    __shared__ float2 lnS[2][64];
    int tid = threadIdx.x;
    int l = tid & 63, w = tid >> 6;
    int chh = w >> 1;
    int rh  = w & 1;
    int lr = l & 15, lq = l >> 4;
    int m0 = blockIdx.x * 64;
    int wbase = tid & ~63;

    int cst = tid & 7;
    int rr  = tid >> 3;
    int gr2[2];
#pragma unroll
    for (int it = 0; it < 2; ++it) {
        int gr = m0 + it * 32 + rr;
        gr2[it] = gr < Bc ? gr : Bc - 1;
    }

    // prologue: stage chunk 0
    {
#pragma unroll
        for (int it = 0; it < 4; ++it)
            gld_lds16(Wimg + (size_t)(it * 256 + tid) * 8,
                      Bs[0] + (size_t)(it * 256 + wbase) * 16);
#pragma unroll
        for (int it = 0; it < 2; ++it) {
            int r = it * 32 + rr;
            uint4 va = *(const uint4*)(Hc + (size_t)gr2[it] * 512 + cst * 8);
            *(uint4*)(As[0] + r * 128 + ((cst ^ (r & 7)) * 16)) = va;
        }
    }
    __syncthreads();

    floatx4 acc[4][2];
#pragma unroll
    for (int i = 0; i < 4; ++i)
#pragma unroll
        for (int j = 0; j < 2; ++j) acc[i][j] = (floatx4)0.f;

    for (int k0c = 0; k0c < 8; ++k0c) {
        int cur = k0c & 1, nb = cur ^ 1;
        uint4 van[2];
        if (k0c < 7) {
            const ushort* img = Wimg + (size_t)(k0c + 1) * 8192;
#pragma unroll
            for (int it = 0; it < 4; ++it)
                gld_lds16(img + (size_t)(it * 256 + tid) * 8,
                          Bs[nb] + (size_t)(it * 256 + wbase) * 16);
#pragma unroll
            for (int it = 0; it < 2; ++it)
                van[it] = *(const uint4*)(Hc + (size_t)gr2[it] * 512
                                          + (k0c + 1) * 64 + cst * 8);
        }
        const char* Asb = As[cur];
        const char* Bsb = Bs[cur];
#pragma unroll
        for (int kk = 0; kk < 2; ++kk) {
            bf16x8 wf[4], af[2];
            int ca = kk * 4 + lq;
#pragma unroll
            for (int i = 0; i < 4; ++i) {
                int rb = chh * 64 + i * 16 + lr;
                wf[i] = *(const bf16x8*)(Bsb + rb * 128 + ((ca ^ (rb & 7)) * 16));
            }
#pragma unroll
            for (int j = 0; j < 2; ++j) {
                int ra = rh * 32 + j * 16 + lr;
                af[j] = *(const bf16x8*)(Asb + ra * 128 + ((ca ^ (ra & 7)) * 16));
            }
#pragma unroll
            for (int i = 0; i < 4; ++i)
#pragma unroll
                for (int j = 0; j < 2; ++j)
                    acc[i][j] = __builtin_amdgcn_mfma_f32_16x16x32_bf16(
                        wf[i], af[j], acc[i][j], 0, 0, 0);
        }
        if (k0c < 7) {
#pragma unroll
            for (int it = 0; it < 2; ++it) {
                int r = it * 32 + rr;
                *(uint4*)(As[nb] + r * 128 + ((cst ^ (r & 7)) * 16)) = van[it];
            }
        }
        __syncthreads();
    }

    int chb[4], arow[2];
#pragma unroll
    for (int i = 0; i < 4; ++i) chb[i] = chh * 64 + i * 16 + lq * 4;
#pragma unroll
    for (int j = 0; j < 2; ++j) arow[j] = m0 + rh * 32 + j * 16 + lr;

    {
        float4 bias[4], gv[4], bv[4];
#pragma unroll
        for (int i = 0; i < 4; ++i) {
            bias[i] = *(const float4*)(e0 + chb[i]);
            gv[i]   = *(const float4*)(lng + chb[i]);
            bv[i]   = *(const float4*)(lnb + chb[i]);
        }
#pragma unroll
        for (int j = 0; j < 2; ++j) {
            int br = arow[j] < Bc ? arow[j] : Bc - 1;
            int sb_ = lenp[br] - 1;
            const ushort* rbase = Xres + ((size_t)br * SEQ + sb_) * 128;
#pragma unroll
            for (int i = 0; i < 4; ++i) {
                ushort4 r4 = *(const ushort4*)(rbase + chb[i]);
                acc[i][j][0] += ((const float*)&bias[i])[0] + bf2f(r4.x);
                acc[i][j][1] += ((const float*)&bias[i])[1] + bf2f(r4.y);
                acc[i][j][2] += ((const float*)&bias[i])[2] + bf2f(r4.z);
                acc[i][j][3] += ((const float*)&bias[i])[3] + bf2f(r4.w);
            }
        }
#pragma unroll
        for (int j = 0; j < 2; ++j) {
            float s = 0.f, q = 0.f;
#pragma unroll
            for (int i = 0; i < 4; ++i)
#pragma unroll
                for (int reg = 0; reg < 4; ++reg) {
                    float v = acc[i][j][reg];
                    s += v; q += v * v;
                }
            s += __shfl_xor(s, 16); q += __shfl_xor(q, 16);
            s += __shfl_xor(s, 32); q += __shfl_xor(q, 32);
            if (lq == 0) lnS[chh][rh * 32 + j * 16 + lr] = make_float2(s, q);
        }
        __syncthreads();
#pragma unroll
        for (int j = 0; j < 2; ++j) {
            int rl = rh * 32 + j * 16 + lr;
            float2 s0 = lnS[0][rl], s1 = lnS[1][rl];
            float mu  = (s0.x + s1.x) * (1.0f / 128.0f);
            float var = (s0.y + s1.y) * (1.0f / 128.0f) - mu * mu;
            float rstd = rsqrtf(var + 1e-5f);
            if (arow[j] < Bc) {
#pragma unroll
                for (int i = 0; i < 4; ++i) {
                    uint2 u;
                    u.x = pkbf((acc[i][j][0] - mu) * rstd * ((const float*)&gv[i])[0] + ((const float*)&bv[i])[0],
                               (acc[i][j][1] - mu) * rstd * ((const float*)&gv[i])[1] + ((const float*)&bv[i])[1]);
                    u.y = pkbf((acc[i][j][2] - mu) * rstd * ((const float*)&gv[i])[2] + ((const float*)&bv[i])[2],
                               (acc[i][j][3] - mu) * rstd * ((const float*)&gv[i])[3] + ((const float*)&bv[i])[3]);
                    *(uint2*)(xc + (size_t)arow[j] * 128 + chb[i]) = u;
                }
            }
        }
    }
}

// ---------------------------------------------------------------------------
// Fused FFN v8 (R26): double-buffered weight staging (Bs[2]), prefetch
// distance 1.
// ---------------------------------------------------------------------------
__global__ __launch_bounds__(256) void ffn_fused_kernel(
    ushort* __restrict__ X, const ushort* __restrict__ W1,
    const ushort* __restrict__ W2,
    const float* __restrict__ b1, const float* __restrict__ b2,
    const float* __restrict__ lng, const float* __restrict__ lnb,
    int Mtot, const int* __restrict__ rowmap, const int* __restrict__ totalp,
    float* __restrict__ outp, int b0f)
{
    int m0 = blockIdx.x * 32;
    int total = totalp ? totalp[0] : Mtot;
    if (m0 >= total) return;
    __shared__ __align__(16) char Bs[2][32768];  // double-buffered weights
    __shared__ ushort Ps[32 * 136];              // P tile, row stride 136
    __shared__ float2 lnS[4][32];
    int tid = threadIdx.x;
    int l = tid & 63, w = tid >> 6;              // 4 waves
    int chh = w;                                 // channel quarter 0..3
    int lr = l & 15, lq = l >> 4;
    int wbase = tid & ~63;                       // wave-uniform chunk base

    // issue stage 0 (W1 chunk 0) immediately for max overlap
    {
        const ushort* img = W1;
#pragma unroll
        for (int it = 0; it < 8; ++it)
            gld_lds16(img + (size_t)(it * 256 + tid) * 8,
                      Bs[0] + (size_t)(it * 256 + wbase) * 16);
    }

    // logical -> actual row for this thread's 2 rows (block covers 32 rows)
    int arow[2], rmrow[2];
#pragma unroll
    for (int j = 0; j < 2; ++j) {
        arow[j] = m0 + j * 16 + lr;
        int rc = arow[j] < total ? arow[j] : total - 1;
        rmrow[j] = rowmap ? rowmap[rc] : rc;
    }

    bf16x8 af_x[8];
#pragma unroll
    for (int j = 0; j < 2; ++j)
#pragma unroll
        for (int kk2 = 0; kk2 < 4; ++kk2) {
            int k = kk2 * 32 + lq * 8;
            af_x[(j << 2) | kk2] = *(const bf16x8*)(X + (size_t)rmrow[j] * 128 + k);
        }

    floatx4 acc2[2][2];
#pragma unroll
    for (int i = 0; i < 2; ++i)
#pragma unroll
        for (int j = 0; j < 2; ++j) acc2[i][j] = (floatx4)0.f;
    floatx4 acc1[2][2];

#pragma unroll
    for (int s = 0; s < 8; ++s) {
        __syncthreads();                         // publishes stage s (+ Ps hazards)
        if (s < 7) {                             // prefetch stage s+1
            int sn = s + 1;
            const ushort* img = ((sn & 1) ? W2 : W1) + (size_t)(sn >> 1) * 16384;
            char* dst = Bs[sn & 1];
#pragma unroll
            for (int it = 0; it < 8; ++it)
                gld_lds16(img + (size_t)(it * 256 + tid) * 8,
                          dst + (size_t)(it * 256 + wbase) * 16);
        }
        const char* B = Bs[s & 1];
        int ffc = s >> 1;
        if (!(s & 1)) {
            // ---- W1 phase: acc1 = x W1c^T, gelu -> Ps
#pragma unroll
            for (int i = 0; i < 2; ++i)
#pragma unroll
                for (int j = 0; j < 2; ++j) acc1[i][j] = (floatx4)0.f;
#pragma unroll
            for (int kk2 = 0; kk2 < 4; ++kk2) {
                int ca = kk2 * 4 + lq;
                bf16x8 wf[2];
#pragma unroll
                for (int i = 0; i < 2; ++i) {
                    int rb = chh * 32 + i * 16 + lr;
                    wf[i] = *(const bf16x8*)(B + rb * 256 + ((ca ^ (rb & 7)) * 16));
                }
#pragma unroll
                for (int i = 0; i < 2; ++i)
#pragma unroll
                    for (int j = 0; j < 2; ++j)
                        acc1[i][j] = __builtin_amdgcn_mfma_f32_16x16x32_bf16(
                            wf[i], af_x[(j << 2) | kk2], acc1[i][j], 0, 0, 0);
            }
#pragma unroll
            for (int j = 0; j < 2; ++j) {
                int rowl = j * 16 + lr;
#pragma unroll
                for (int i = 0; i < 2; ++i) {
                    int ch0 = chh * 32 + i * 16 + lq * 4;
                    float4 bv = *(const float4*)(b1 + ffc * 128 + ch0);
                    float g0, g1, g2, g3, v;
                    v = acc1[i][j][0] + bv.x; g0 = 0.5f * v * (1.0f + erff(v * 0.70710678118654752f));
                    v = acc1[i][j][1] + bv.y; g1 = 0.5f * v * (1.0f + erff(v * 0.70710678118654752f));
                    v = acc1[i][j][2] + bv.z; g2 = 0.5f * v * (1.0f + erff(v * 0.70710678118654752f));
                    v = acc1[i][j][3] + bv.w; g3 = 0.5f * v * (1.0f + erff(v * 0.70710678118654752f));
                    uint2 u; u.x = pkbf(g0, g1); u.y = pkbf(g2, g3);
                    *(uint2*)(Ps + rowl * 136 + ch0) = u;
                }
            }
        } else {
            // ---- W2 phase: acc2 += P_ffc W2c^T
#pragma unroll
            for (int kk2 = 0; kk2 < 4; ++kk2) {
                int ca = kk2 * 4 + lq;
                bf16x8 wf[2], af[2];
#pragma unroll
                for (int i = 0; i < 2; ++i) {
                    int rb = chh * 32 + i * 16 + lr;
                    wf[i] = *(const bf16x8*)(B + rb * 256 + ((ca ^ (rb & 7)) * 16));
                }
#pragma unroll
                for (int j = 0; j < 2; ++j) {
                    int rowl = j * 16 + lr;
                    af[j] = *(const bf16x8*)(Ps + rowl * 136 + kk2 * 32 + lq * 8);
                }
#pragma unroll
                for (int i = 0; i < 2; ++i)
#pragma unroll
                    for (int j = 0; j < 2; ++j)
                        acc2[i][j] = __builtin_amdgcn_mfma_f32_16x16x32_bf16(
                            wf[i], af[j], acc2[i][j], 0, 0, 0);
            }
        }
    }

    int chb[2];
#pragma unroll
    for (int i = 0; i < 2; ++i) chb[i] = chh * 32 + i * 16 + lq * 4;

    float4 bias[2], gv[2], bv[2];
#pragma unroll
    for (int i = 0; i < 2; ++i) {
        bias[i] = *(const float4*)(b2 + chb[i]);
        gv[i]   = *(const float4*)(lng + chb[i]);
        bv[i]   = *(const float4*)(lnb + chb[i]);
    }
#pragma unroll
    for (int j = 0; j < 2; ++j) {
#pragma unroll
        for (int i = 0; i < 2; ++i) {
            ushort4 r4 = *(const ushort4*)(X + (size_t)rmrow[j] * 128 + chb[i]);
            acc2[i][j][0] += ((const float*)&bias[i])[0] + bf2f(r4.x);
            acc2[i][j][1] += ((const float*)&bias[i])[1] + bf2f(r4.y);
            acc2[i][j][2] += ((const float*)&bias[i])[2] + bf2f(r4.z);
            acc2[i][j][3] += ((const float*)&bias[i])[3] + bf2f(r4.w);
        }
    }
#pragma unroll
    for (int j = 0; j < 2; ++j) {
        float s = 0.f, q = 0.f;
#pragma unroll
        for (int i = 0; i < 2; ++i)
#pragma unroll
            for (int reg = 0; reg < 4; ++reg) {
                float v = acc2[i][j][reg];
                s += v; q += v * v;
            }
        s += __shfl_xor(s, 16); q += __shfl_xor(q, 16);
        s += __shfl_xor(s, 32); q += __shfl_xor(q, 32);
        if (lq == 0) lnS[chh][j * 16 + lr] = make_float2(s, q);
    }
    __syncthreads();
#pragma unroll
    for (int j = 0; j < 2; ++j) {
        int rl = j * 16 + lr;
        float2 s0 = lnS[0][rl], s1 = lnS[1][rl];
        float2 s2 = lnS[2][rl], s3 = lnS[3][rl];
        float mu  = (s0.x + s1.x + s2.x + s3.x) * (1.0f / 128.0f);
        float var = (s0.y + s1.y + s2.y + s3.y) * (1.0f / 128.0f) - mu * mu;
        float rstd = rsqrtf(var + 1e-5f);
        if (arow[j] < total) {
            if (outp) {
#pragma unroll
                for (int i = 0; i < 2; ++i) {
                    float4 o;
                    o.x = (acc2[i][j][0] - mu) * rstd * ((const float*)&gv[i])[0] + ((const float*)&bv[i])[0];
                    o.y = (acc2[i][j][1] - mu) * rstd * ((const float*)&gv[i])[1] + ((const float*)&bv[i])[1];
                    o.z = (acc2[i][j][2] - mu) * rstd * ((const float*)&gv[i])[2] + ((const float*)&bv[i])[2];
                    o.w = (acc2[i][j][3] - mu) * rstd * ((const float*)&gv[i])[3] + ((const float*)&bv[i])[3];
                    *(float4*)(outp + (size_t)(b0f + rmrow[j]) * 128 + chb[i]) = o;
                }
            } else {
#pragma unroll
                for (int i = 0; i < 2; ++i) {
                    uint2 u;
                    u.x = pkbf((acc2[i][j][0] - mu) * rstd * ((const float*)&gv[i])[0] + ((const float*)&bv[i])[0],
                               (acc2[i][j][1] - mu) * rstd * ((const float*)&gv[i])[1] + ((const float*)&bv[i])[1]);
                    u.y = pkbf((acc2[i][j][2] - mu) * rstd * ((const float*)&gv[i])[2] + ((const float*)&bv[i])[2],
                               (acc2[i][j][3] - mu) * rstd * ((const float*)&gv[i])[3] + ((const float*)&bv[i])[3]);
                    *(uint2*)(X + (size_t)rmrow[j] * 128 + chb[i]) = u;
                }
            }
        }
    }
}

// ---------------------------------------------------------------------------
extern "C" void kernel_launch(void* const* d_in, const int* in_sizes, int n_in,
                              void* d_out, int out_size, void* d_ws, size_t ws_size,
                              hipStream_t stream)
{
    const float* token_emb  = (const float*)d_in[0];
    const float* emb_ln_g   = (const float*)d_in[1];
    const float* emb_ln_b   = (const float*)d_in[2];
    const float* params_log = (const float*)d_in[3];
    const float* in_wr      = (const float*)d_in[4];
    const float* in_wi      = (const float*)d_in[5];
    const float* in_br      = (const float*)d_in[6];
    const float* in_bi      = (const float*)d_in[7];
    const float* out_wr     = (const float*)d_in[8];
    const float* out_wi     = (const float*)d_in[9];
    const float* out_br     = (const float*)d_in[10];
    const float* lru_ln_g   = (const float*)d_in[12];
    const float* lru_ln_b   = (const float*)d_in[13];
    const float* w1         = (const float*)d_in[14];
    const float* b1         = (const float*)d_in[15];
    const float* w2         = (const float*)d_in[16];
    const float* b2         = (const float*)d_in[17];
    const float* ffn_ln_g   = (const float*)d_in[18];
    const float* ffn_ln_b   = (const float*)d_in[19];
    const int*   item_seq   = (const int*)d_in[20];
    const int*   item_seq_len = (const int*)d_in[21];
    float* out = (float*)d_out;

    char* ws = (char*)d_ws;
    ushort* Winb   = (ushort*)ws;                      ws += NLAY * 65536 * 2;
    ushort* W2effb = (ushort*)ws;                      ws += NLAY * 65536 * 2;
    ushort* w1b    = (ushort*)ws;                      ws += NLAY * 65536 * 2;
    ushort* w2b    = (ushort*)ws;                      ws += NLAY * 65536 * 2;
    float* lam_pow = (float*)ws;                       ws += NLAY * 65536 * 4;
    float* scale_in = (float*)ws;                      ws += NLAY * 512 * 4;
    float* bias_in  = (float*)ws;                      ws += NLAY * 512 * 4;
    size_t table_bytes = (size_t)(ws - (char*)d_ws);

    int Bc = B_TOT;
    while (Bc > 32) {
        size_t need = table_bytes
                    + (size_t)Bc * SEQ * (D * 2 + 2 * DH * 2)
                    + (size_t)(Bc * SEQ + 8) * 4 + 1024;
        if (need <= ws_size) break;
        Bc >>= 1;
    }
    ushort* xb = (ushort*)ws;                          ws += (size_t)Bc * SEQ * D * 2;
    ushort* hb = (ushort*)ws;                          ws += (size_t)Bc * SEQ * 2 * DH * 2;
    int* totalp = (int*)ws;                            ws += 8 * 4;
    int* rowmap = (int*)ws;
    ushort* Hc = hb;                                   // compact H (Bc*512), aliases hb
    ushort* xc = hb + (size_t)Bc * 512;                // compact x (Bc*128)

    setup_all_kernel<<<NLAY * 65536 / 256, 256, 0, stream>>>(
        params_log, in_br, in_bi, in_wr, in_wi, out_wr, out_wi, w1, w2,
        Winb, W2effb, w1b, w2b, lam_pow, scale_in, bias_in);

    for (int b0 = 0; b0 < B_TOT; b0 += Bc) {
        int M = Bc * SEQ;
        const int* lenp = item_seq_len + b0;
        embed_ln_kernel<<<M / 4 + 1, 256, 0, stream>>>(
            token_emb, item_seq + (size_t)b0 * SEQ, lenp,
            emb_ln_g, emb_ln_b, xb, Bc, totalp, rowmap);

        for (int li = 0; li < NLAY; ++li) {
            if (li < NLAY - 1) {
                inproj_scan_kernel<false><<<dim3(16, Bc), 512, 0, stream>>>(
                    xb, Winb + (size_t)li * 65536, hb,
                    (const float2*)(lam_pow + (size_t)li * 65536),
                    item_seq + (size_t)b0 * SEQ, lenp,
                    scale_in + li * 512, bias_in + li * 512);
                outproj_kernel<<<dim3(M / 64), 256, 0, stream>>>(
                    hb, W2effb + (size_t)li * 65536, xb, rowmap, totalp,
                    out_br + li * D, xb,
                    lru_ln_g + li * D, lru_ln_b + li * D);
                ffn_fused_kernel<<<dim3(M / 32), 256, 0, stream>>>(
                    xb, w1b + (size_t)li * 65536, w2b + (size_t)li * 65536,
                    b1 + li * DFF, b2 + li * D,
                    ffn_ln_g + li * D, ffn_ln_b + li * D, M, rowmap, totalp,
                    (float*)0, 0);
            } else {
                inproj_scan_kernel<true><<<dim3(16, Bc), 512, 0, stream>>>(
                    xb, Winb + (size_t)li * 65536, Hc,
                    (const float2*)(lam_pow + (size_t)li * 65536),
                    item_seq + (size_t)b0 * SEQ, lenp,
                    scale_in + li * 512, bias_in + li * 512);
                outproj_last_kernel<<<dim3((Bc + 63) / 64), 256, 0, stream>>>(
                    Hc, W2effb + (size_t)li * 65536, xc, Bc,
                    out_br + li * D, xb, lenp,
                    lru_ln_g + li * D, lru_ln_b + li * D);
                ffn_fused_kernel<<<dim3((Bc + 31) / 32), 256, 0, stream>>>(
                    xc, w1b + (size_t)li * 65536, w2b + (size_t)li * 65536,
                    b1 + li * DFF, b2 + li * D,
                    ffn_ln_g + li * D, ffn_ln_b + li * D, Bc,
                    (const int*)0, (const int*)0, out, b0);
            }
        }
    }
}

// Round 8
// 362.991 us; speedup vs baseline: 1.0417x; 1.0417x over previous
//
#include <hip/hip_runtime.h>
#include <hip/hip_bf16.h>
#include <math.h>

#define B_TOT 512
#define SEQ   200
#define D     128
#define DH    256
#define DFF   512
#define LPAD  256
#define PADL  56
#define NLAY  2
#define SSTRIP 140  // scan LDS strip stride (floats): strip = 8 pos x 16 ch + pad

typedef __attribute__((ext_vector_type(8))) short bf16x8;
typedef __attribute__((ext_vector_type(4))) float floatx4;
typedef __attribute__((ext_vector_type(2))) float floatx2;

static __device__ inline float bf2f(ushort u) {
    union { unsigned int i; float f; } v; v.i = ((unsigned int)u) << 16; return v.f;
}
static __device__ inline ushort f2bf(float x) {
    union { float f; unsigned int i; } v; v.f = x;
    unsigned int r = (v.i + 0x7FFFu + ((v.i >> 16) & 1u)) >> 16;   // RNE
    return (ushort)r;
}
// HW packed f32x2 -> bf16x2 (v_cvt_pk_bf16_f32 on gfx950), RNE
static __device__ inline unsigned int pkbf(float a, float b) {
    union { __hip_bfloat162 h; unsigned int u; } v;
    v.h = __float22bfloat162_rn(make_float2(a, b));
    return v.u;
}
// async global->LDS, 16B per lane; LDS dest = wave-uniform base + lane*16
static __device__ inline void gld_lds16(const void* g, void* l) {
    __builtin_amdgcn_global_load_lds(
        (const __attribute__((address_space(1))) unsigned int*)g,
        (__attribute__((address_space(3))) unsigned int*)l, 16, 0, 0);
}

// H layout: [b][g(8)][p(re/im)][s(200)][32 ch] bf16. k in 0..511: k<256 re, else im.
static __device__ inline size_t haddr(int b, int s, int k) {
    int p  = k >> 8;
    int ch = k & 255;
    int g  = ch >> 5;
    int cl = ch & 31;
    return (((((size_t)b * 8 + g) * 2 + p) * SEQ + s) * 32 + cl);
}

// ---------------------------------------------------------------------------
// Unified setup: pre-swizzled weight images + lambda powers/scales.
// ---------------------------------------------------------------------------
__global__ void setup_all_kernel(const float* __restrict__ params_log,
                                 const float* __restrict__ in_br,
                                 const float* __restrict__ in_bi,
                                 const float* __restrict__ in_wr,
                                 const float* __restrict__ in_wi,
                                 const float* __restrict__ out_wr,
                                 const float* __restrict__ out_wi,
                                 const float* __restrict__ w1,
                                 const float* __restrict__ w2,
                                 ushort* __restrict__ Winb,
                                 ushort* __restrict__ W2effb,
                                 ushort* __restrict__ w1b,
                                 ushort* __restrict__ w2b,
                                 float* __restrict__ lam_pow,
                                 float* __restrict__ scale_in,
                                 float* __restrict__ bias_in)
{
    int idx = blockIdx.x * blockDim.x + threadIdx.x;   // NLAY*65536
    int li = idx >> 16;
    int e  = idx & 65535;

    {   // inproj Ws image
        int gp = e >> 12, rem = e & 4095;
        int q = rem >> 3, e8 = rem & 7;
        int r = q >> 4, cs = q & 15;
        int c16 = cs ^ (r & 7);
        int n = (r < 16) ? (gp * 16 + r) : (256 + gp * 16 + (r - 16));
        int d = c16 * 8 + e8;
        float wv = (n < DH) ? in_wr[((size_t)li * DH + n) * D + d]
                            : in_wi[((size_t)li * DH + (n - DH)) * D + d];
        Winb[idx] = f2bf(wv);
    }
    {   // out-proj W2eff image
        int k0c = e >> 13, rem = e & 8191;
        int q = rem >> 3, e8 = rem & 7;
        int r = q >> 3, cs = q & 7;
        int c16 = cs ^ (r & 7);
        int k = k0c * 64 + c16 * 8 + e8;
        float w2v = (k < DH) ? out_wr[((size_t)li * D + r) * DH + k]
                             : -out_wi[((size_t)li * D + r) * DH + (k - DH)];
        W2effb[idx] = f2bf(w2v);
    }
    {   // ffn W1 image: logical [512][128]
        int row = e >> 7, col = e & 127;
        int ffc = row >> 7, rl = row & 127;
        int c16 = col >> 3, e8 = col & 7;
        int cs = c16 ^ (rl & 7);
        w1b[li * 65536 + ffc * 16384 + rl * 128 + cs * 8 + e8] = f2bf(w1[idx]);
    }
    {   // ffn W2 image: logical [128][512]
        int dd2 = e >> 9, kk = e & 511;
        int ffc = kk >> 7, klc = kk & 127;
        int c16 = klc >> 3, e8 = klc & 7;
        int cs = c16 ^ (dd2 & 7);
        w2b[li * 65536 + ffc * 16384 + dd2 * 128 + cs * 8 + e8] = f2bf(w2[idx]);
    }

    if (blockIdx.x < NLAY) {
        int pli = blockIdx.x;
        int c = threadIdx.x;
        const float* pl = params_log + (size_t)pli * 3 * DH;
        float nu = expf(pl[c]);
        float th = expf(pl[DH + c]);
        float ga = expf(pl[2 * DH + c]);
        float mag = expf(-nu);
        float lr = mag * cosf(th);
        float lim = mag * sinf(th);
        float2* lp = (float2*)(lam_pow + (size_t)pli * 65536) + (size_t)c * 128;
        float pr = lr, pi = lim;
        lp[0] = make_float2(pr, pi);
        for (int k = 1; k < 128; ++k) {
            float nr = pr * lr - pi * lim;
            float ni = pr * lim + pi * lr;
            pr = nr; pi = ni;
            lp[k] = make_float2(pr, pi);
        }
        scale_in[pli * 2 * DH + c]      = ga;
        scale_in[pli * 2 * DH + DH + c] = ga;
        bias_in[pli * 2 * DH + c]       = in_br[pli * DH + c] * ga;
        bias_in[pli * 2 * DH + DH + c]  = in_bi[pli * DH + c] * ga;
    }
}

// ---------------------------------------------------------------------------
// Embedding gather + LayerNorm -> bf16 x (R20: skip causally dead rows).
// R24: the LAST block instead builds the compacted rowmap (fused, -1 kernel).
// ---------------------------------------------------------------------------
__global__ __launch_bounds__(256) void embed_ln_kernel(
    const float* __restrict__ emb, const int* __restrict__ seq,
    const int* __restrict__ lenp,
    const float* __restrict__ g, const float* __restrict__ bt,
    ushort* __restrict__ x,
    int Bc, int* __restrict__ total, int* __restrict__ rowmap)
{
    if (blockIdx.x == gridDim.x - 1) {
        // rowmap build: prefix scan of lengths (pair-per-thread, Bc <= 512)
        __shared__ int ps[257];
        int t = threadIdx.x;
        int b0_ = 2 * t, b1_ = 2 * t + 1;
        int lv0 = (b0_ < Bc) ? lenp[b0_] : 0;
        int lv1 = (b1_ < Bc) ? lenp[b1_] : 0;
        ps[t + 1] = lv0 + lv1;
        if (t == 0) ps[0] = 0;
        __syncthreads();
        for (int ofs = 1; ofs < 256; ofs <<= 1) {
            int v = ps[t + 1];
            int vv = (t + 1 > ofs) ? ps[t + 1 - ofs] : 0;
            __syncthreads();
            ps[t + 1] = v + vv;
            __syncthreads();
        }
        if (t == 255) total[0] = ps[256];
        int base = ps[t];
        int rb0 = b0_ * SEQ, rb1 = b1_ * SEQ;
        for (int s = 0; s < lv0; ++s) rowmap[base + s] = rb0 + s;
        base += lv0;
        for (int s = 0; s < lv1; ++s) rowmap[base + s] = rb1 + s;
        return;
    }
    int row  = blockIdx.x * 4 + (threadIdx.x >> 6);
    int lane = threadIdx.x & 63;
    int b = row / SEQ, s = row - b * SEQ;
    if (s >= lenp[b]) return;
    int item = seq[row];
    float2 v = *(const float2*)(emb + (size_t)item * D + lane * 2);
    float ssum = v.x + v.y;
#pragma unroll
    for (int o = 32; o > 0; o >>= 1) ssum += __shfl_xor(ssum, o);
    float mu = ssum * (1.0f / D);
    float d0 = v.x - mu, d1 = v.y - mu;
    float vs = d0 * d0 + d1 * d1;
#pragma unroll
    for (int o = 32; o > 0; o >>= 1) vs += __shfl_xor(vs, o);
    float rstd = rsqrtf(vs * (1.0f / D) + 1e-5f);
    float2 gg = *(const float2*)(g + lane * 2);
    float2 bb = *(const float2*)(bt + lane * 2);
    unsigned int o2 = pkbf(d0 * rstd * gg.x + bb.x, d1 * rstd * gg.y + bb.y);
    *(unsigned int*)(x + (size_t)row * D + lane * 2) = o2;
}

// ---------------------------------------------------------------------------
// FUSED in-proj + exact tree scan (R24 strip layout + shuffle tree).
// R27: XCD-aware bijective block swizzle (FETCH 55.7->8.5 MB confirmed).
// R29: R28's lambda-hoist + single-phase branch REVERTED (occupancy/VGPR
// regression: 70->54%, 32->40 VGPR, dur +9%).
// ---------------------------------------------------------------------------
template <bool LAST>
__global__ __launch_bounds__(512) void inproj_scan_kernel(
    const ushort* __restrict__ X, const ushort* __restrict__ Win,
    ushort* __restrict__ H, const float2* __restrict__ lamT,
    const int* __restrict__ seq, const int* __restrict__ lenp,
    const float* __restrict__ scale_in, const float* __restrict__ bias_in)
{
    __shared__ __align__(16) char smem[36864];   // Ws 8192 + xs 28672 (phase A)
    __shared__ __align__(16) float mkfS[32 * 12];
    char*  Wsm = smem;                           // [32][128] bf16, swizzled
    char*  xs  = smem + 8192;                    // [112][128] bf16, swizzled
    float* stR2 = (float*)smem;                  // strip layout, 4480 floats
    float* stI2 = stR2 + 32 * SSTRIP;            // ends at 35840 B

    // XCD swizzle (bijective: nwg = 16*Bc is divisible by 8)
    int flat = blockIdx.y * 16 + blockIdx.x;
    int cpx  = (gridDim.y * 16) >> 3;
    int swz  = (flat & 7) * cpx + (flat >> 3);
    int gp = swz & 15, b = swz >> 4;

    int tid = threadIdx.x;
    int l = tid & 63, w = tid >> 6;              // 8 waves
    int ct = w & 1;                              // 0=re tile, 1=im tile
    int rq = w >> 1;                             // row quarter 0..3
    int lr = l & 15, lq = l >> 4;
    int wbase = tid & ~63;

    int c  = tid >> 5;                           // scan channel 0..15
    int tl = tid & 31;                           // chunk 0..31 (in-wave)
    int t0 = tl * 8;
    int lbase = l & 32;                          // channel-half base lane
    int coff = (c >> 2) * 36 + (c & 3) * 8;      // channel offset within strip

    // R20 causal bounds (block-uniform)
    int s_b = lenp[b] - 1;                       // 0..199
    int tile_max = s_b >> 4;                     // needed MFMA tiles 0..tile_max
    int nrows = (tile_max + 1) * 16;             // staged rows (tile-rounded)
    int tb = s_b + PADL;                         // last needed padded position
    bool activeT = (t0 <= tb);

    // ---- Phase A: async Ws stage + x stage A (rows 0..min(112,nrows))
    const ushort* xrow = X + (size_t)b * SEQ * 128;
    gld_lds16(Win + (size_t)gp * 4096 + (size_t)tid * 8,
              Wsm + (size_t)wbase * 16);
    int nrA = nrows < 112 ? nrows : 112;
#pragma unroll
    for (int it = 0; it < 4; ++it) {
        int rbase = it * 32 + w * 4;             // wave-uniform base row
        int r = rbase + lq;
        int cs = lr ^ (r & 7);
        if (r < nrA)
            gld_lds16(xrow + (size_t)r * 128 + cs * 8, xs + rbase * 256);
    }

    const float2* myl = lamT + (size_t)(gp * 16 + c) * 128;

    if (tid < LPAD) {
        int t = tid;
        float m = 0.f;
        if (t >= PADL) m = (seq[(size_t)b * SEQ + (t - PADL)] > 0) ? 1.f : 0.f;
        mkfS[(t >> 3) * 12 + (t & 7)] = m;
    }
    __syncthreads();

    bf16x8 wf[4];
#pragma unroll
    for (int kk = 0; kk < 4; ++kk) {
        int ca = kk * 4 + lq;
        int wr = ct * 16 + lr;
        wf[kk] = *(const bf16x8*)(Wsm + wr * 256 + ((ca ^ (wr & 7)) * 16));
    }
    int tstart = rq ? (3 * rq + 1) : 0;          // 0 / 4 / 7 / 10
    int tcnt   = rq ? 3 : 4;
    floatx4 acc[4];
#pragma unroll
    for (int tt = 0; tt < 4; ++tt) acc[tt] = (floatx4)0.f;

    if (rq < 2) {
#pragma unroll
        for (int tt = 0; tt < 4; ++tt) {
            if (tt < tcnt && (tstart + tt) <= tile_max) {
                int t  = tstart + tt;
                int ar = t * 16 + lr;
#pragma unroll
                for (int kk = 0; kk < 4; ++kk) {
                    int ca = kk * 4 + lq;
                    bf16x8 af = *(const bf16x8*)(xs + ar * 256 + ((ca ^ (ar & 7)) * 16));
                    acc[tt] = __builtin_amdgcn_mfma_f32_16x16x32_bf16(wf[kk], af, acc[tt], 0, 0, 0);
                }
            }
        }
    }
    __syncthreads();

    // stage B: rows 112..nrows-1 -> xs local rows 0..
    if (nrows > 112) {
        int nrB = nrows < 200 ? nrows : 200;
#pragma unroll
        for (int it = 0; it < 3; ++it) {
            int rbase = it * 32 + w * 4;         // local rows 0..95
            int rl_ = rbase + lq;
            int gr = 112 + rl_;
            int cs = lr ^ (rl_ & 7);
            if (gr < nrB)
                gld_lds16(xrow + (size_t)gr * 128 + cs * 8, xs + rbase * 256);
        }
    }
    __syncthreads();

    if (rq >= 2) {
#pragma unroll
        for (int tt = 0; tt < 4; ++tt) {
            if (tt < tcnt && (tstart + tt) <= tile_max) {
                int t  = tstart + tt;
                int ar = (t - 7) * 16 + lr;
#pragma unroll
                for (int kk = 0; kk < 4; ++kk) {
                    int ca = kk * 4 + lq;
                    bf16x8 af = *(const bf16x8*)(xs + ar * 256 + ((ca ^ (ar & 7)) * 16));
                    acc[tt] = __builtin_amdgcn_mfma_f32_16x16x32_bf16(wf[kk], af, acc[tt], 0, 0, 0);
                }
            }
        }
    }
    __syncthreads();

    // lambda-power prefetch (L2-resident table), after MFMA phase
    float2 l14[4];
#pragma unroll
    for (int k = 0; k < 4; ++k) l14[k] = myl[k];
    float2 myl9 = myl[8];
    float2 lam_e[3];                             // levels half=32/64/128
#pragma unroll
    for (int i = 0; i < 3; ++i) {
        int half = 32 << i;
        int off = t0 & ((half << 1) - 1);
        int e = off - half;
        lam_e[i] = myl[e < 0 ? 0 : e];
    }
    float2 l7;                                   // lambda^7 = l^4 * l^3
    l7.x = l14[3].x * l14[2].x - l14[3].y * l14[2].y;
    l7.y = l14[3].x * l14[2].y + l14[3].y * l14[2].x;

    // ---- Phase B: zero pad strips (pos 0..55 = strips 0..6) + epilogue
    for (int idx = tid; idx < 7 * SSTRIP; idx += 512) { stR2[idx] = 0.f; stI2[idx] = 0.f; }
    {
        float4 g4 = *(const float4*)(scale_in + ct * 256 + gp * 16 + lq * 4);
        float4 b4 = *(const float4*)(bias_in  + ct * 256 + gp * 16 + lq * 4);
        float* base = ct ? stI2 : stR2;
#pragma unroll
        for (int tt = 0; tt < 4; ++tt) {
            if (tt < tcnt && (tstart + tt) <= tile_max) {
                int t = tstart + tt;
                int s = t * 16 + lr;
                if (s <= s_b) {
                    // pos = s + 56; strip = 2t+7+(lr>>3); off = lr&7
                    float* dst = base + (2 * t + 7 + (lr >> 3)) * SSTRIP
                               + lq * 36 + (lr & 7);
                    dst[0]  = acc[tt][0] * g4.x + b4.x;
                    dst[8]  = acc[tt][1] * g4.y + b4.y;
                    dst[16] = acc[tt][2] * g4.z + b4.z;
                    dst[24] = acc[tt][3] * g4.w + b4.w;
                }
            }
        }
    }
    __syncthreads();

    // ---- Scan: conflict-free b128 loads, pair-packed levels, shuffle tree
    floatx2 Xr[4], Xi[4], Mf[4];
    {
        const float* pr = stR2 + tl * SSTRIP + coff;
        const float* pi = stI2 + tl * SSTRIP + coff;
        floatx4 r0 = *(const floatx4*)pr;
        floatx4 r1 = *(const floatx4*)(pr + 4);
        floatx4 i0 = *(const floatx4*)pi;
        floatx4 i1 = *(const floatx4*)(pi + 4);
        floatx4 m0 = *(const floatx4*)(mkfS + tl * 12);
        floatx4 m1 = *(const floatx4*)(mkfS + tl * 12 + 4);
        Xr[0] = floatx2{r0[0], r0[1]}; Xr[1] = floatx2{r0[2], r0[3]};
        Xr[2] = floatx2{r1[0], r1[1]}; Xr[3] = floatx2{r1[2], r1[3]};
        Xi[0] = floatx2{i0[0], i0[1]}; Xi[1] = floatx2{i0[2], i0[3]};
        Xi[2] = floatx2{i1[0], i1[1]}; Xi[3] = floatx2{i1[2], i1[3]};
        Mf[0] = floatx2{m0[0], m0[1]}; Mf[1] = floatx2{m0[2], m0[3]};
        Mf[2] = floatx2{m1[0], m1[1]}; Mf[3] = floatx2{m1[2], m1[3]};
    }

    float l0x = l14[0].x, l0y = l14[0].y;
    floatx2 L01R = floatx2{l14[0].x, l14[1].x};
    floatx2 L01I = floatx2{l14[0].y, l14[1].y};
    floatx2 L23R = floatx2{l14[2].x, l14[3].x};
    floatx2 L23I = floatx2{l14[2].y, l14[3].y};

    if (activeT) {
        // level 1: even -> odd within pairs (scalar)
#pragma unroll
        for (int p = 0; p < 4; ++p) {
            float sr = Xr[p].x * Mf[p].x, si = Xi[p].x * Mf[p].x;
            Xr[p].y += l0x * sr; Xr[p].y -= l0y * si;
            Xi[p].y += l0x * si; Xi[p].y += l0y * sr;
        }
        // level 2: src x1 -> pair1, src x5 -> pair3 (packed)
#pragma unroll
        for (int p = 0; p < 2; ++p) {
            int sp_ = p * 2;                     // source pair 0 / 2
            float sr = Xr[sp_].y * Mf[sp_].y, si = Xi[sp_].y * Mf[sp_].y;
            Xr[sp_ + 1] += sr * L01R; Xr[sp_ + 1] -= si * L01I;
            Xi[sp_ + 1] += si * L01R; Xi[sp_ + 1] += sr * L01I;
        }
        // level 3: src x3 -> pairs 2,3 (packed)
        {
            float sr = Xr[1].y * Mf[1].y, si = Xi[1].y * Mf[1].y;
            Xr[2] += sr * L01R; Xr[2] -= si * L01I;
            Xi[2] += si * L01R; Xi[2] += sr * L01I;
            Xr[3] += sr * L23R; Xr[3] -= si * L23I;
            Xi[3] += si * L23R; Xi[3] += sr * L23I;
        }
    }

    // levels 4-8 via intra-wave shuffles on x7 (scalar, lazy carry)
    float x7r, x7i;
    if (activeT) { x7r = Xr[3].y; x7i = Xi[3].y; }
    else         { x7r = 0.f;     x7i = 0.f; }
    float Ctr = 0.f, Cti = 0.f;
    float m7 = Mf[3].y;
    float pxr = x7r * m7, pxi = x7i * m7;

#define TREE_LEVEL(SRC_TL, TGT, LE)                                          \
    {                                                                        \
        int srcl = lbase | (SRC_TL);                                         \
        float svx = __shfl(pxr, srcl);                                       \
        float svy = __shfl(pxi, srcl);                                       \
        if (activeT && (TGT)) {                                              \
            float2 le = (LE);                                                \
            float cr = le.x * svx - le.y * svy;                              \
            float ci = le.x * svy + le.y * svx;                              \
            Ctr += cr; Cti += ci;                                            \
            x7r += l7.x * cr - l7.y * ci;                                    \
            x7i += l7.x * ci + l7.y * cr;                                    \
            pxr = x7r * m7; pxi = x7i * m7;                                  \
        }                                                                    \
    }

    TREE_LEVEL(tl & ~1,          tl & 1,  l14[0]);                   // half=8
    TREE_LEVEL((tl & ~3)  | 1,   tl & 2,  (tl & 1) ? myl9 : l14[0]); // half=16
    TREE_LEVEL((tl & ~7)  | 3,   tl & 4,  lam_e[0]);                 // half=32
    if (tb >= 64)  TREE_LEVEL((tl & ~15) | 7,  tl & 8,  lam_e[1]);   // half=64
    if (tb >= 128) TREE_LEVEL((tl & ~31) | 15, tl & 16, lam_e[2]);   // half=128
#undef TREE_LEVEL

    // apply accumulated carry to positions 0..6 (x7 already exact)
    if (activeT && (!LAST || (unsigned)(tb - t0) < 7u)) {
        float2 l5, l6;
        l5.x = l14[3].x * l14[0].x - l14[3].y * l14[0].y;
        l5.y = l14[3].x * l14[0].y + l14[3].y * l14[0].x;
        l6.x = l14[3].x * l14[1].x - l14[3].y * l14[1].y;
        l6.y = l14[3].x * l14[1].y + l14[3].y * l14[1].x;
        Xr[0].x += Ctr;                                 Xi[0].x += Cti;
        Xr[0].y += l14[0].x * Ctr; Xr[0].y -= l14[0].y * Cti;
        Xi[0].y += l14[0].x * Cti; Xi[0].y += l14[0].y * Ctr;
        Xr[1].x += l14[1].x * Ctr; Xr[1].x -= l14[1].y * Cti;
        Xi[1].x += l14[1].x * Cti; Xi[1].x += l14[1].y * Ctr;
        Xr[1].y += l14[2].x * Ctr; Xr[1].y -= l14[2].y * Cti;
        Xi[1].y += l14[2].x * Cti; Xi[1].y += l14[2].y * Ctr;
        Xr[2].x += l14[3].x * Ctr; Xr[2].x -= l14[3].y * Cti;
        Xi[2].x += l14[3].x * Cti; Xi[2].x += l14[3].y * Ctr;
        Xr[2].y += l5.x * Ctr;     Xr[2].y -= l5.y * Cti;
        Xi[2].y += l5.x * Cti;     Xi[2].y += l5.y * Ctr;
        Xr[3].x += l6.x * Ctr;     Xr[3].x -= l6.y * Cti;
        Xi[3].x += l6.x * Cti;     Xi[3].x += l6.y * Ctr;
    }
    Xr[3].y = x7r; Xi[3].y = x7i;

    if (LAST) {
        // only position tb is consumed downstream
        if (activeT && (unsigned)(tb - t0) < 8u) {
#pragma unroll
            for (int k = 0; k < 8; ++k)
                if (t0 + k == tb) {
                    float vr = (k & 1) ? Xr[k >> 1].y : Xr[k >> 1].x;
                    float vi = (k & 1) ? Xi[k >> 1].y : Xi[k >> 1].x;
                    stR2[tl * SSTRIP + coff + k] = vr;
                    stI2[tl * SSTRIP + coff + k] = vi;
                }
        }
    } else {
        // pad threads (chunks fully < PADL) write rows never read
        if (activeT && tl >= 7) {
            floatx4 r0 = floatx4{Xr[0].x, Xr[0].y, Xr[1].x, Xr[1].y};
            floatx4 r1 = floatx4{Xr[2].x, Xr[2].y, Xr[3].x, Xr[3].y};
            floatx4 i0 = floatx4{Xi[0].x, Xi[0].y, Xi[1].x, Xi[1].y};
            floatx4 i1 = floatx4{Xi[2].x, Xi[2].y, Xi[3].x, Xi[3].y};
            *(floatx4*)(stR2 + tl * SSTRIP + coff)     = r0;
            *(floatx4*)(stR2 + tl * SSTRIP + coff + 4) = r1;
            *(floatx4*)(stI2 + tl * SSTRIP + coff)     = i0;
            *(floatx4*)(stI2 + tl * SSTRIP + coff + 4) = i1;
        }
    }
    __syncthreads();

    if (LAST) {
        if (tid < 32) {
            int p = tid >> 4, cc = tid & 15;
            int fi = (tb >> 3) * SSTRIP + (cc >> 2) * 36 + (cc & 3) * 8 + (tb & 7);
            float v = (p ? stI2 : stR2)[fi];
            H[(size_t)b * 512 + p * 256 + gp * 16 + cc] = f2bf(v);
        }
    } else {
        int g  = gp >> 1;
        int hc = (gp & 1) * 16;
        ushort* baseg = H + (size_t)(b * 8 + g) * 2 * SEQ * 32 + hc;
#pragma unroll
        for (int it = 0; it < 4; ++it) {
            int idx4 = it * 512 + tid;
            if (idx4 < 2 * SEQ * 4) {
                int q  = idx4 & 3;
                int ps = idx4 >> 2;
                int p  = ps >= SEQ;
                int s  = ps - p * SEQ;
                if (s > s_b) continue;           // causally dead, never read
                // pos = s + 56: strip = (s+56)>>3, off = s&7 (56 % 8 == 0)
                const float* sp = (p ? stI2 : stR2)
                                + ((s + PADL) >> 3) * SSTRIP + q * 36 + (s & 7);
                float a0 = sp[0], a1 = sp[8], a2 = sp[16], a3 = sp[24];
                uint2 raw;
                raw.x = pkbf(a0, a1);
                raw.y = pkbf(a2, a3);
                *(uint2*)(baseg + (size_t)ps * 32 + q * 4) = raw;
            }
        }
    }
}

// ---------------------------------------------------------------------------
// Out-proj GEMM (full path). R25 single-buffer: 64-row M-tile, 256 threads
// (4 waves = 2 ch-halves x 2 row-halves), LDS 25.6KB -> 6 blocks/CU.
// (R27's dbuf reverted — no confirmed net win; TLP already hides stalls.)
// ---------------------------------------------------------------------------
__global__ __launch_bounds__(256) void outproj_kernel(
    const ushort* __restrict__ A, const ushort* __restrict__ Wimg,
    ushort* __restrict__ Cout,
    const int* __restrict__ rowmap, const int* __restrict__ totalp,
    const float* __restrict__ e0,
    const ushort* __restrict__ res,
    const float* __restrict__ lng, const float* __restrict__ lnb)
{
    int m0 = blockIdx.x * 64;
    int total = totalp[0];
    if (m0 >= total) return;
    __shared__ __align__(16) char As[8192];      // 64 rows x 64k bf16, swizzled
    __shared__ __align__(16) char Bs[16384];     // 128 d x 64k bf16, swizzled
    __shared__ float2 lnS[2][64];
    int tid = threadIdx.x;
    int l = tid & 63, w = tid >> 6;              // 4 waves
    int chh = w >> 1;                            // ch half 0..1 (64 ch)
    int rh  = w & 1;                             // row half 0..1 (32 rows)
    int lr = l & 15, lq = l >> 4;
    int wbase = tid & ~63;

    int cst = tid & 7;
    int rr  = tid >> 3;                          // 0..31
    int sb[2], ss[2];
#pragma unroll
    for (int it = 0; it < 2; ++it) {
        int gr = m0 + it * 32 + rr;
        if (gr >= total) gr = total - 1;
        int rm = rowmap[gr];
        sb[it] = rm / SEQ; ss[it] = rm - sb[it] * SEQ;
    }

    floatx4 acc[4][2];
#pragma unroll
    for (int i = 0; i < 4; ++i)
#pragma unroll
        for (int j = 0; j < 2; ++j) acc[i][j] = (floatx4)0.f;

    for (int k0c = 0; k0c < 8; ++k0c) {
        int k0 = k0c * 64;
        {
            const ushort* img = Wimg + (size_t)k0c * 8192;
#pragma unroll
            for (int it = 0; it < 4; ++it)
                gld_lds16(img + (size_t)(it * 256 + tid) * 8,
                          Bs + (size_t)(it * 256 + wbase) * 16);
        }
#pragma unroll
        for (int it = 0; it < 2; ++it) {
            int r = it * 32 + rr;
            uint4 va = *(const uint4*)(A + haddr(sb[it], ss[it], k0 + cst * 8));
            *(uint4*)(As + r * 128 + ((cst ^ (r & 7)) * 16)) = va;
        }
        __syncthreads();
#pragma unroll
        for (int kk = 0; kk < 2; ++kk) {
            bf16x8 wf[4], af[2];
            int ca = kk * 4 + lq;
#pragma unroll
            for (int i = 0; i < 4; ++i) {
                int rb = chh * 64 + i * 16 + lr;
                wf[i] = *(const bf16x8*)(Bs + rb * 128 + ((ca ^ (rb & 7)) * 16));
            }
#pragma unroll
            for (int j = 0; j < 2; ++j) {
                int ra = rh * 32 + j * 16 + lr;
                af[j] = *(const bf16x8*)(As + ra * 128 + ((ca ^ (ra & 7)) * 16));
            }
#pragma unroll
            for (int i = 0; i < 4; ++i)
#pragma unroll
                for (int j = 0; j < 2; ++j)
                    acc[i][j] = __builtin_amdgcn_mfma_f32_16x16x32_bf16(
                        wf[i], af[j], acc[i][j], 0, 0, 0);
        }
        __syncthreads();
    }

    int chb[4], arow[2], rmj[2];
#pragma unroll
    for (int i = 0; i < 4; ++i) chb[i] = chh * 64 + i * 16 + lq * 4;
#pragma unroll
    for (int j = 0; j < 2; ++j) {
        arow[j] = m0 + rh * 32 + j * 16 + lr;
        int rc = arow[j] < total ? arow[j] : total - 1;
        rmj[j] = rowmap[rc];
    }

    {
        float4 bias[4], gv[4], bv[4];
#pragma unroll
        for (int i = 0; i < 4; ++i) {
            bias[i] = *(const float4*)(e0 + chb[i]);
            gv[i]   = *(const float4*)(lng + chb[i]);
            bv[i]   = *(const float4*)(lnb + chb[i]);
        }
#pragma unroll
        for (int j = 0; j < 2; ++j) {
#pragma unroll
            for (int i = 0; i < 4; ++i) {
                ushort4 r4 = *(const ushort4*)(res + (size_t)rmj[j] * 128 + chb[i]);
                acc[i][j][0] += ((const float*)&bias[i])[0] + bf2f(r4.x);
                acc[i][j][1] += ((const float*)&bias[i])[1] + bf2f(r4.y);
                acc[i][j][2] += ((const float*)&bias[i])[2] + bf2f(r4.z);
                acc[i][j][3] += ((const float*)&bias[i])[3] + bf2f(r4.w);
            }
        }
#pragma unroll
        for (int j = 0; j < 2; ++j) {
            float s = 0.f, q = 0.f;
#pragma unroll
            for (int i = 0; i < 4; ++i)
#pragma unroll
                for (int reg = 0; reg < 4; ++reg) {
                    float v = acc[i][j][reg];
                    s += v; q += v * v;
                }
            s += __shfl_xor(s, 16); q += __shfl_xor(q, 16);
            s += __shfl_xor(s, 32); q += __shfl_xor(q, 32);
            if (lq == 0) lnS[chh][rh * 32 + j * 16 + lr] = make_float2(s, q);
        }
        __syncthreads();
#pragma unroll
        for (int j = 0; j < 2; ++j) {
            int rl = rh * 32 + j * 16 + lr;
            float2 s0 = lnS[0][rl], s1 = lnS[1][rl];
            float mu  = (s0.x + s1.x) * (1.0f / 128.0f);
            float var = (s0.y + s1.y) * (1.0f / 128.0f) - mu * mu;
            float rstd = rsqrtf(var + 1e-5f);
            if (arow[j] < total) {
#pragma unroll
                for (int i = 0; i < 4; ++i) {
                    uint2 u;
                    u.x = pkbf((acc[i][j][0] - mu) * rstd * ((const float*)&gv[i])[0] + ((const float*)&bv[i])[0],
                               (acc[i][j][1] - mu) * rstd * ((const float*)&gv[i])[1] + ((const float*)&bv[i])[1]);
                    u.y = pkbf((acc[i][j][2] - mu) * rstd * ((const float*)&gv[i])[2] + ((const float*)&bv[i])[2],
                               (acc[i][j][3] - mu) * rstd * ((const float*)&gv[i])[3] + ((const float*)&bv[i])[3]);
                    *(uint2*)(Cout + (size_t)rmj[j] * 128 + chb[i]) = u;
                }
            }
        }
    }
}

// ---------------------------------------------------------------------------
// Out-proj LAST (R19): compact M=Bc rows from Hc[b][512]. R25 single-buffer.
// ---------------------------------------------------------------------------
__global__ __launch_bounds__(256) void outproj_last_kernel(
    const ushort* __restrict__ Hc, const ushort* __restrict__ Wimg,
    ushort* __restrict__ xc, int Bc,
    const float* __restrict__ e0,
    const ushort* __restrict__ Xres, const int* __restrict__ lenp,
    const float* __restrict__ lng, const float* __restrict__ lnb)
{
    __shared__ __align__(16) char As[8192];
    __shared__ __align__(16) char Bs[16384];
    __shared__ float2 lnS[2][64];
    int tid = threadIdx.x;
    int l = tid & 63, w = tid >> 6;
    int chh = w >> 1;
    int rh  = w & 1;
    int lr = l & 15, lq = l >> 4;
    int m0 = blockIdx.x * 64;
    int wbase = tid & ~63;

    int cst = tid & 7;
    int rr  = tid >> 3;

    floatx4 acc[4][2];
#pragma unroll
    for (int i = 0; i < 4; ++i)
#pragma unroll
        for (int j = 0; j < 2; ++j) acc[i][j] = (floatx4)0.f;

    for (int k0c = 0; k0c < 8; ++k0c) {
        int k0 = k0c * 64;
        {
            const ushort* img = Wimg + (size_t)k0c * 8192;
#pragma unroll
            for (int it = 0; it < 4; ++it)
                gld_lds16(img + (size_t)(it * 256 + tid) * 8,
                          Bs + (size_t)(it * 256 + wbase) * 16);
        }
#pragma unroll
        for (int it = 0; it < 2; ++it) {
            int r = it * 32 + rr;
            int gr = m0 + r; if (gr >= Bc) gr = Bc - 1;
            uint4 va = *(const uint4*)(Hc + (size_t)gr * 512 + k0 + cst * 8);
            *(uint4*)(As + r * 128 + ((cst ^ (r & 7)) * 16)) = va;
        }
        __syncthreads();
#pragma unroll
        for (int kk = 0; kk < 2; ++kk) {
            bf16x8 wf[4], af[2];
            int ca = kk * 4 + lq;
#pragma unroll
            for (int i = 0; i < 4; ++i) {
                int rb = chh * 64 + i * 16 + lr;
                wf[i] = *(const bf16x8*)(Bs + rb * 128 + ((ca ^ (rb & 7)) * 16));
            }
#pragma unroll
            for (int j = 0; j < 2; ++j) {
                int ra = rh * 32 + j * 16 + lr;
                af[j] = *(const bf16x8*)(As + ra * 128 + ((ca ^ (ra & 7)) * 16));
            }
#pragma unroll
            for (int i = 0; i < 4; ++i)
#pragma unroll
                for (int j = 0; j < 2; ++j)
                    acc[i][j] = __builtin_amdgcn_mfma_f32_16x16x32_bf16(
                        wf[i], af[j], acc[i][j], 0, 0, 0);
        }
        __syncthreads();
    }

    int chb[4], arow[2];
#pragma unroll
    for (int i = 0; i < 4; ++i) chb[i] = chh * 64 + i * 16 + lq * 4;
#pragma unroll
    for (int j = 0; j < 2; ++j) arow[j] = m0 + rh * 32 + j * 16 + lr;

    {
        float4 bias[4], gv[4], bv[4];
#pragma unroll
        for (int i = 0; i < 4; ++i) {
            bias[i] = *(const float4*)(e0 + chb[i]);
            gv[i]   = *(const float4*)(lng + chb[i]);
            bv[i]   = *(const float4*)(lnb + chb[i]);
        }
#pragma unroll
        for (int j = 0; j < 2; ++j) {
            int br = arow[j] < Bc ? arow[j] : Bc - 1;
            int sb_ = lenp[br] - 1;
            const ushort* rbase = Xres + ((size_t)br * SEQ + sb_) * 128;
#pragma unroll
            for (int i = 0; i < 4; ++i) {
                ushort4 r4 = *(const ushort4*)(rbase + chb[i]);
                acc[i][j][0] += ((const float*)&bias[i])[0] + bf2f(r4.x);
                acc[i][j][1] += ((const float*)&bias[i])[1] + bf2f(r4.y);
                acc[i][j][2] += ((const float*)&bias[i])[2] + bf2f(r4.z);
                acc[i][j][3] += ((const float*)&bias[i])[3] + bf2f(r4.w);
            }
        }
#pragma unroll
        for (int j = 0; j < 2; ++j) {
            float s = 0.f, q = 0.f;
#pragma unroll
            for (int i = 0; i < 4; ++i)
#pragma unroll
                for (int reg = 0; reg < 4; ++reg) {
                    float v = acc[i][j][reg];
                    s += v; q += v * v;
                }
            s += __shfl_xor(s, 16); q += __shfl_xor(q, 16);
            s += __shfl_xor(s, 32); q += __shfl_xor(q, 32);
            if (lq == 0) lnS[chh][rh * 32 + j * 16 + lr] = make_float2(s, q);
        }
        __syncthreads();
#pragma unroll
        for (int j = 0; j < 2; ++j) {
            int rl = rh * 32 + j * 16 + lr;
            float2 s0 = lnS[0][rl], s1 = lnS[1][rl];
            float mu  = (s0.x + s1.x) * (1.0f / 128.0f);
            float var = (s0.y + s1.y) * (1.0f / 128.0f) - mu * mu;
            float rstd = rsqrtf(var + 1e-5f);
            if (arow[j] < Bc) {
#pragma unroll
                for (int i = 0; i < 4; ++i) {
                    uint2 u;
                    u.x = pkbf((acc[i][j][0] - mu) * rstd * ((const float*)&gv[i])[0] + ((const float*)&bv[i])[0],
                               (acc[i][j][1] - mu) * rstd * ((const float*)&gv[i])[1] + ((const float*)&bv[i])[1]);
                    u.y = pkbf((acc[i][j][2] - mu) * rstd * ((const float*)&gv[i])[2] + ((const float*)&bv[i])[2],
                               (acc[i][j][3] - mu) * rstd * ((const float*)&gv[i])[3] + ((const float*)&bv[i])[3]);
                    *(uint2*)(xc + (size_t)arow[j] * 128 + chb[i]) = u;
                }
            }
        }
    }
}

// ---------------------------------------------------------------------------
// Fused FFN v7 (R25 single-buffer): 32-row M-tile, 256 threads = 4 waves,
// each wave owns a 32-channel quarter; 42.5KB LDS -> 3 blocks/CU.
// (R26's dbuf reverted — per-dispatch gain never showed in total; dropped
// occupancy 3->2 blocks/CU.) outp != nullptr -> final f32 write.
// ---------------------------------------------------------------------------
__global__ __launch_bounds__(256) void ffn_fused_kernel(
    ushort* __restrict__ X, const ushort* __restrict__ W1,
    const ushort* __restrict__ W2,
    const float* __restrict__ b1, const float* __restrict__ b2,
    const float* __restrict__ lng, const float* __restrict__ lnb,
    int Mtot, const int* __restrict__ rowmap, const int* __restrict__ totalp,
    float* __restrict__ outp, int b0f)
{
    int m0 = blockIdx.x * 32;
    int total = totalp ? totalp[0] : Mtot;
    if (m0 >= total) return;
    __shared__ __align__(16) char Bs[32768];   // pre-swizzled 32KB weight chunk
    __shared__ ushort Ps[32 * 136];            // P tile, row stride 136 (8.5KB)
    __shared__ float2 lnS[4][32];
    int tid = threadIdx.x;
    int l = tid & 63, w = tid >> 6;            // 4 waves
    int chh = w;                               // channel quarter 0..3 (32 ch)
    int lr = l & 15, lq = l >> 4;
    int wbase = tid & ~63;                     // wave-uniform chunk base

    // logical -> actual row for this thread's 2 rows (block covers 32 rows)
    int arow[2], rmrow[2];
#pragma unroll
    for (int j = 0; j < 2; ++j) {
        arow[j] = m0 + j * 16 + lr;
        int rc = arow[j] < total ? arow[j] : total - 1;
        rmrow[j] = rowmap ? rowmap[rc] : rc;
    }

    bf16x8 af_x[8];
#pragma unroll
    for (int j = 0; j < 2; ++j)
#pragma unroll
        for (int kk2 = 0; kk2 < 4; ++kk2) {
            int k = kk2 * 32 + lq * 8;
            af_x[(j << 2) | kk2] = *(const bf16x8*)(X + (size_t)rmrow[j] * 128 + k);
        }

    floatx4 acc2[2][2];
#pragma unroll
    for (int i = 0; i < 2; ++i)
#pragma unroll
        for (int j = 0; j < 2; ++j) acc2[i][j] = (floatx4)0.f;

    for (int ffc = 0; ffc < 4; ++ffc) {
        if (ffc) __syncthreads();
        {
            const ushort* img = W1 + (size_t)ffc * 16384;
#pragma unroll
            for (int it = 0; it < 8; ++it)
                gld_lds16(img + (size_t)(it * 256 + tid) * 8,
                          Bs + (size_t)(it * 256 + wbase) * 16);
        }
        __syncthreads();

        floatx4 acc1[2][2];
#pragma unroll
        for (int i = 0; i < 2; ++i)
#pragma unroll
            for (int j = 0; j < 2; ++j) acc1[i][j] = (floatx4)0.f;
#pragma unroll
        for (int kk2 = 0; kk2 < 4; ++kk2) {
            int ca = kk2 * 4 + lq;
            bf16x8 wf[2];
#pragma unroll
            for (int i = 0; i < 2; ++i) {
                int rb = chh * 32 + i * 16 + lr;
                wf[i] = *(const bf16x8*)(Bs + rb * 256 + ((ca ^ (rb & 7)) * 16));
            }
#pragma unroll
            for (int i = 0; i < 2; ++i)
#pragma unroll
                for (int j = 0; j < 2; ++j)
                    acc1[i][j] = __builtin_amdgcn_mfma_f32_16x16x32_bf16(
                        wf[i], af_x[(j << 2) | kk2], acc1[i][j], 0, 0, 0);
        }

#pragma unroll
        for (int j = 0; j < 2; ++j) {
            int rowl = j * 16 + lr;
#pragma unroll
            for (int i = 0; i < 2; ++i) {
                int ch0 = chh * 32 + i * 16 + lq * 4;
                float4 bv = *(const float4*)(b1 + ffc * 128 + ch0);
                float g0, g1, g2, g3, v;
                v = acc1[i][j][0] + bv.x; g0 = 0.5f * v * (1.0f + erff(v * 0.70710678118654752f));
                v = acc1[i][j][1] + bv.y; g1 = 0.5f * v * (1.0f + erff(v * 0.70710678118654752f));
                v = acc1[i][j][2] + bv.z; g2 = 0.5f * v * (1.0f + erff(v * 0.70710678118654752f));
                v = acc1[i][j][3] + bv.w; g3 = 0.5f * v * (1.0f + erff(v * 0.70710678118654752f));
                uint2 u; u.x = pkbf(g0, g1); u.y = pkbf(g2, g3);
                *(uint2*)(Ps + rowl * 136 + ch0) = u;
            }
        }
        __syncthreads();

        {
            const ushort* img = W2 + (size_t)ffc * 16384;
#pragma unroll
            for (int it = 0; it < 8; ++it)
                gld_lds16(img + (size_t)(it * 256 + tid) * 8,
                          Bs + (size_t)(it * 256 + wbase) * 16);
        }
        __syncthreads();

#pragma unroll
        for (int kk2 = 0; kk2 < 4; ++kk2) {
            int ca = kk2 * 4 + lq;
            bf16x8 wf[2], af[2];
#pragma unroll
            for (int i = 0; i < 2; ++i) {
                int rb = chh * 32 + i * 16 + lr;
                wf[i] = *(const bf16x8*)(Bs + rb * 256 + ((ca ^ (rb & 7)) * 16));
            }
#pragma unroll
            for (int j = 0; j < 2; ++j) {
                int rowl = j * 16 + lr;
                af[j] = *(const bf16x8*)(Ps + rowl * 136 + kk2 * 32 + lq * 8);
            }
#pragma unroll
            for (int i = 0; i < 2; ++i)
#pragma unroll
                for (int j = 0; j < 2; ++j)
                    acc2[i][j] = __builtin_amdgcn_mfma_f32_16x16x32_bf16(
                        wf[i], af[j], acc2[i][j], 0, 0, 0);
        }
    }

    int chb[2];
#pragma unroll
    for (int i = 0; i < 2; ++i) chb[i] = chh * 32 + i * 16 + lq * 4;

    float4 bias[2], gv[2], bv[2];
#pragma unroll
    for (int i = 0; i < 2; ++i) {
        bias[i] = *(const float4*)(b2 + chb[i]);
        gv[i]   = *(const float4*)(lng + chb[i]);
        bv[i]   = *(const float4*)(lnb + chb[i]);
    }
#pragma unroll
    for (int j = 0; j < 2; ++j) {
#pragma unroll
        for (int i = 0; i < 2; ++i) {
            ushort4 r4 = *(const ushort4*)(X + (size_t)rmrow[j] * 128 + chb[i]);
            acc2[i][j][0] += ((const float*)&bias[i])[0] + bf2f(r4.x);
            acc2[i][j][1] += ((const float*)&bias[i])[1] + bf2f(r4.y);
            acc2[i][j][2] += ((const float*)&bias[i])[2] + bf2f(r4.z);
            acc2[i][j][3] += ((const float*)&bias[i])[3] + bf2f(r4.w);
        }
    }
#pragma unroll
    for (int j = 0; j < 2; ++j) {
        float s = 0.f, q = 0.f;
#pragma unroll
        for (int i = 0; i < 2; ++i)
#pragma unroll
            for (int reg = 0; reg < 4; ++reg) {
                float v = acc2[i][j][reg];
                s += v; q += v * v;
            }
        s += __shfl_xor(s, 16); q += __shfl_xor(q, 16);
        s += __shfl_xor(s, 32); q += __shfl_xor(q, 32);
        if (lq == 0) lnS[chh][j * 16 + lr] = make_float2(s, q);
    }
    __syncthreads();
#pragma unroll
    for (int j = 0; j < 2; ++j) {
        int rl = j * 16 + lr;
        float2 s0 = lnS[0][rl], s1 = lnS[1][rl];
        float2 s2 = lnS[2][rl], s3 = lnS[3][rl];
        float mu  = (s0.x + s1.x + s2.x + s3.x) * (1.0f / 128.0f);
        float var = (s0.y + s1.y + s2.y + s3.y) * (1.0f / 128.0f) - mu * mu;
        float rstd = rsqrtf(var + 1e-5f);
        if (arow[j] < total) {
            if (outp) {
#pragma unroll
                for (int i = 0; i < 2; ++i) {
                    float4 o;
                    o.x = (acc2[i][j][0] - mu) * rstd * ((const float*)&gv[i])[0] + ((const float*)&bv[i])[0];
                    o.y = (acc2[i][j][1] - mu) * rstd * ((const float*)&gv[i])[1] + ((const float*)&bv[i])[1];
                    o.z = (acc2[i][j][2] - mu) * rstd * ((const float*)&gv[i])[2] + ((const float*)&bv[i])[2];
                    o.w = (acc2[i][j][3] - mu) * rstd * ((const float*)&gv[i])[3] + ((const float*)&bv[i])[3];
                    *(float4*)(outp + (size_t)(b0f + rmrow[j]) * 128 + chb[i]) = o;
                }
            } else {
#pragma unroll
                for (int i = 0; i < 2; ++i) {
                    uint2 u;
                    u.x = pkbf((acc2[i][j][0] - mu) * rstd * ((const float*)&gv[i])[0] + ((const float*)&bv[i])[0],
                               (acc2[i][j][1] - mu) * rstd * ((const float*)&gv[i])[1] + ((const float*)&bv[i])[1]);
                    u.y = pkbf((acc2[i][j][2] - mu) * rstd * ((const float*)&gv[i])[2] + ((const float*)&bv[i])[2],
                               (acc2[i][j][3] - mu) * rstd * ((const float*)&gv[i])[3] + ((const float*)&bv[i])[3]);
                    *(uint2*)(X + (size_t)rmrow[j] * 128 + chb[i]) = u;
                }
            }
        }
    }
}

// ---------------------------------------------------------------------------
extern "C" void kernel_launch(void* const* d_in, const int* in_sizes, int n_in,
                              void* d_out, int out_size, void* d_ws, size_t ws_size,
                              hipStream_t stream)
{
    const float* token_emb  = (const float*)d_in[0];
    const float* emb_ln_g   = (const float*)d_in[1];
    const float* emb_ln_b   = (const float*)d_in[2];
    const float* params_log = (const float*)d_in[3];
    const float* in_wr      = (const float*)d_in[4];
    const float* in_wi      = (const float*)d_in[5];
    const float* in_br      = (const float*)d_in[6];
    const float* in_bi      = (const float*)d_in[7];
    const float* out_wr     = (const float*)d_in[8];
    const float* out_wi     = (const float*)d_in[9];
    const float* out_br     = (const float*)d_in[10];
    const float* lru_ln_g   = (const float*)d_in[12];
    const float* lru_ln_b   = (const float*)d_in[13];
    const float* w1         = (const float*)d_in[14];
    const float* b1         = (const float*)d_in[15];
    const float* w2         = (const float*)d_in[16];
    const float* b2         = (const float*)d_in[17];
    const float* ffn_ln_g   = (const float*)d_in[18];
    const float* ffn_ln_b   = (const float*)d_in[19];
    const int*   item_seq   = (const int*)d_in[20];
    const int*   item_seq_len = (const int*)d_in[21];
    float* out = (float*)d_out;

    char* ws = (char*)d_ws;
    ushort* Winb   = (ushort*)ws;                      ws += NLAY * 65536 * 2;
    ushort* W2effb = (ushort*)ws;                      ws += NLAY * 65536 * 2;
    ushort* w1b    = (ushort*)ws;                      ws += NLAY * 65536 * 2;
    ushort* w2b    = (ushort*)ws;                      ws += NLAY * 65536 * 2;
    float* lam_pow = (float*)ws;                       ws += NLAY * 65536 * 4;
    float* scale_in = (float*)ws;                      ws += NLAY * 512 * 4;
    float* bias_in  = (float*)ws;                      ws += NLAY * 512 * 4;
    size_t table_bytes = (size_t)(ws - (char*)d_ws);

    int Bc = B_TOT;
    while (Bc > 32) {
        size_t need = table_bytes
                    + (size_t)Bc * SEQ * (D * 2 + 2 * DH * 2)
                    + (size_t)(Bc * SEQ + 8) * 4 + 1024;
        if (need <= ws_size) break;
        Bc >>= 1;
    }
    ushort* xb = (ushort*)ws;                          ws += (size_t)Bc * SEQ * D * 2;
    ushort* hb = (ushort*)ws;                          ws += (size_t)Bc * SEQ * 2 * DH * 2;
    int* totalp = (int*)ws;                            ws += 8 * 4;
    int* rowmap = (int*)ws;
    ushort* Hc = hb;                                   // compact H (Bc*512), aliases hb
    ushort* xc = hb + (size_t)Bc * 512;                // compact x (Bc*128)

    setup_all_kernel<<<NLAY * 65536 / 256, 256, 0, stream>>>(
        params_log, in_br, in_bi, in_wr, in_wi, out_wr, out_wi, w1, w2,
        Winb, W2effb, w1b, w2b, lam_pow, scale_in, bias_in);

    for (int b0 = 0; b0 < B_TOT; b0 += Bc) {
        int M = Bc * SEQ;
        const int* lenp = item_seq_len + b0;
        embed_ln_kernel<<<M / 4 + 1, 256, 0, stream>>>(
            token_emb, item_seq + (size_t)b0 * SEQ, lenp,
            emb_ln_g, emb_ln_b, xb, Bc, totalp, rowmap);

        for (int li = 0; li < NLAY; ++li) {
            if (li < NLAY - 1) {
                inproj_scan_kernel<false><<<dim3(16, Bc), 512, 0, stream>>>(
                    xb, Winb + (size_t)li * 65536, hb,
                    (const float2*)(lam_pow + (size_t)li * 65536),
                    item_seq + (size_t)b0 * SEQ, lenp,
                    scale_in + li * 512, bias_in + li * 512);
                outproj_kernel<<<dim3(M / 64), 256, 0, stream>>>(
                    hb, W2effb + (size_t)li * 65536, xb, rowmap, totalp,
                    out_br + li * D, xb,
                    lru_ln_g + li * D, lru_ln_b + li * D);
                ffn_fused_kernel<<<dim3(M / 32), 256, 0, stream>>>(
                    xb, w1b + (size_t)li * 65536, w2b + (size_t)li * 65536,
                    b1 + li * DFF, b2 + li * D,
                    ffn_ln_g + li * D, ffn_ln_b + li * D, M, rowmap, totalp,
                    (float*)0, 0);
            } else {
                inproj_scan_kernel<true><<<dim3(16, Bc), 512, 0, stream>>>(
                    xb, Winb + (size_t)li * 65536, Hc,
                    (const float2*)(lam_pow + (size_t)li * 65536),
                    item_seq + (size_t)b0 * SEQ, lenp,
                    scale_in + li * 512, bias_in + li * 512);
                outproj_last_kernel<<<dim3((Bc + 63) / 64), 256, 0, stream>>>(
                    Hc, W2effb + (size_t)li * 65536, xc, Bc,
                    out_br + li * D, xb, lenp,
                    lru_ln_g + li * D, lru_ln_b + li * D);
                ffn_fused_kernel<<<dim3((Bc + 31) / 32), 256, 0, stream>>>(
                    xc, w1b + (size_t)li * 65536, w2b + (size_t)li * 65536,
                    b1 + li * DFF, b2 + li * D,
                    ffn_ln_g + li * D, ffn_ln_b + li * D, Bc,
                    (const int*)0, (const int*)0, out, b0);
            }
        }
    }
}